// Round 1
// baseline (341.460 us; speedup 1.0000x reference)
//
#include <hip/hip_runtime.h>
#include <hip/hip_bf16.h>

// Problem constants
#define BS 256
#define EMB 768
#define HW 196          // 14*14
#define NMASK 16
#define HID 4096
#define OUT 256
#define NPROJ 4
#define MROWS 4096      // BS*NMASK

typedef __attribute__((ext_vector_type(8))) short bf16x8;   // 8 bf16 in 4 VGPRs
typedef __attribute__((ext_vector_type(4))) float f32x4;
typedef __attribute__((ext_vector_type(8))) unsigned short u16x8;

__device__ inline float bf2f(unsigned short u) {
    unsigned int x = ((unsigned int)u) << 16;
    return __builtin_bit_cast(float, x);
}
__device__ inline unsigned short f2bf(float f) {
    __hip_bfloat16 h = __float2bfloat16(f);
    return __builtin_bit_cast(unsigned short, h);
}

// async global->LDS, 16B per lane; lds base must be wave-uniform
#define GL16(gptr, lptr)                                                     \
    __builtin_amdgcn_global_load_lds(                                        \
        (const __attribute__((address_space(1))) void*)(gptr),               \
        (__attribute__((address_space(3))) void*)(lptr), 16, 0, 0)

// ---------------------------------------------------------------------------
// Kernel 1: masked mean pooling.  pooled[b*16+n][e] = (1/area) sum_hw m*x
// x: [BS][EMB][HW] f32, masks: [BS][NMASK][HW] f32 -> pooled bf16 [4096][768]
// ---------------------------------------------------------------------------
__global__ __launch_bounds__(256) void pool_kernel(
    const float* __restrict__ x, const float* __restrict__ masks,
    __hip_bfloat16* __restrict__ pooled)
{
    __shared__ float msk[NMASK][HW + 1];   // stride 197: 5 mod 32 -> conflict-free
    __shared__ float xs[64][HW + 1];
    __shared__ float inv[NMASK];
    const int b = blockIdx.x, tid = threadIdx.x;

    const float* mp = masks + (size_t)b * NMASK * HW;
    for (int i = tid; i < NMASK * HW; i += 256) msk[i / HW][i % HW] = mp[i];
    __syncthreads();
    if (tid < NMASK) {
        float a = 0.f;
        for (int hw = 0; hw < HW; ++hw) a += msk[tid][hw];
        inv[tid] = 1.0f / fmaxf(a, 1.0f);
    }
    __syncthreads();

    const int e_l = tid & 63, ng = tid >> 6;   // wave-uniform ng
    for (int e0 = 0; e0 < EMB; e0 += 64) {
        __syncthreads();   // protect xs from previous iteration readers
        const float* xp = x + ((size_t)b * EMB + e0) * HW;
        for (int i = tid; i < 64 * HW; i += 256) xs[i / HW][i % HW] = xp[i];
        __syncthreads();
        float a0 = 0.f, a1 = 0.f, a2 = 0.f, a3 = 0.f;
        #pragma unroll 4
        for (int hw = 0; hw < HW; ++hw) {
            float xv = xs[e_l][hw];
            a0 += xv * msk[ng * 4 + 0][hw];
            a1 += xv * msk[ng * 4 + 1][hw];
            a2 += xv * msk[ng * 4 + 2][hw];
            a3 += xv * msk[ng * 4 + 3][hw];
        }
        size_t base = (size_t)b * NMASK * EMB + e0 + e_l;
        pooled[base + (size_t)(ng * 4 + 0) * EMB] = __float2bfloat16(a0 * inv[ng * 4 + 0]);
        pooled[base + (size_t)(ng * 4 + 1) * EMB] = __float2bfloat16(a1 * inv[ng * 4 + 1]);
        pooled[base + (size_t)(ng * 4 + 2) * EMB] = __float2bfloat16(a2 * inv[ng * 4 + 2]);
        pooled[base + (size_t)(ng * 4 + 3) * EMB] = __float2bfloat16(a3 * inv[ng * 4 + 3]);
    }
}

// ---------------------------------------------------------------------------
// Kernel 2: transpose + f32->bf16.  src [gz][R][C] f32 -> dst [gz][C][R] bf16
// R, C multiples of 64
// ---------------------------------------------------------------------------
__global__ __launch_bounds__(256) void transpose_cvt(
    const float* __restrict__ src, __hip_bfloat16* __restrict__ dst, int R, int C)
{
    __shared__ float tile[64][65];
    const float* s = src + (size_t)blockIdx.z * R * C;
    __hip_bfloat16* d = dst + (size_t)blockIdx.z * R * C;
    const int c0 = blockIdx.x * 64, r0 = blockIdx.y * 64, tid = threadIdx.x;
    for (int i = tid; i < 4096; i += 256) {
        int r = i >> 6, c = i & 63;
        tile[r][c] = s[(size_t)(r0 + r) * C + c0 + c];
    }
    __syncthreads();
    for (int i = tid; i < 4096; i += 256) {
        int c = i >> 6, r = i & 63;
        d[(size_t)(c0 + c) * R + r0 + r] = __float2bfloat16(tile[r][c]);
    }
}

// ---------------------------------------------------------------------------
// Kernel 3: GEMM1 h[p] = pooled @ W1[p]  (128x128 tile, BK=32, 4 waves 2x2)
// A = pooled bf16 [4096][768]; BT = W1T bf16 [4][4096][768] (K-contiguous)
// Epilogue: column sum/sumsq atomics (BN stats) + store selected rows to h_sel
// ---------------------------------------------------------------------------
__global__ __launch_bounds__(256) void gemm1(
    const __hip_bfloat16* __restrict__ A, const __hip_bfloat16* __restrict__ BT,
    const int* __restrict__ proj,
    float* __restrict__ ssum, float* __restrict__ ssq,
    __hip_bfloat16* __restrict__ h_sel)
{
    __shared__ __align__(16) __hip_bfloat16 As[128 * 32];
    __shared__ __align__(16) __hip_bfloat16 Bs[128 * 32];
    const int tid = threadIdx.x, lane = tid & 63, wid = tid >> 6;
    const int p = blockIdx.z;
    const int n0 = blockIdx.x * 128, m0 = blockIdx.y * 128;
    const __hip_bfloat16* Bp = BT + (size_t)p * HID * EMB;
    const int wr = wid >> 1, wc = wid & 1;
    const int l4 = lane >> 4, lc = lane & 15;

    f32x4 acc[4][4] = {};

    for (int k0 = 0; k0 < EMB; k0 += 32) {
        __syncthreads();
        #pragma unroll
        for (int r = 0; r < 2; ++r) {
            int t = r * 256 + tid;
            int row = t >> 2, ko = (t & 3) * 8;
            GL16(A + (size_t)(m0 + row) * EMB + k0 + ko, &As[(r * 256 + wid * 64) * 8]);
        }
        #pragma unroll
        for (int r = 0; r < 2; ++r) {
            int t = r * 256 + tid;
            int row = t >> 2, ko = (t & 3) * 8;
            GL16(Bp + (size_t)(n0 + row) * EMB + k0 + ko, &Bs[(r * 256 + wid * 64) * 8]);
        }
        __syncthreads();
        const bf16x8* Av = (const bf16x8*)As;
        const bf16x8* Bv = (const bf16x8*)Bs;
        bf16x8 a[4], b[4];
        #pragma unroll
        for (int m = 0; m < 4; ++m) a[m] = Av[(wr * 64 + m * 16 + lc) * 4 + l4];
        #pragma unroll
        for (int n = 0; n < 4; ++n) b[n] = Bv[(wc * 64 + n * 16 + lc) * 4 + l4];
        #pragma unroll
        for (int m = 0; m < 4; ++m)
            #pragma unroll
            for (int n = 0; n < 4; ++n)
                acc[m][n] = __builtin_amdgcn_mfma_f32_16x16x32_bf16(a[m], b[n], acc[m][n], 0, 0, 0);
    }

    // ---- epilogue: BN stats (per-column sum, sumsq over this block's 128 rows)
    #pragma unroll
    for (int n = 0; n < 4; ++n) {
        int col = n0 + wc * 64 + n * 16 + lc;
        float s1 = 0.f, s2 = 0.f;
        #pragma unroll
        for (int m = 0; m < 4; ++m)
            #pragma unroll
            for (int j = 0; j < 4; ++j) { float v = acc[m][n][j]; s1 += v; s2 += v * v; }
        s1 += __shfl_xor(s1, 16); s1 += __shfl_xor(s1, 32);
        s2 += __shfl_xor(s2, 16); s2 += __shfl_xor(s2, 32);
        if (lane < 16) {
            atomicAdd(&ssum[p * HID + col], s1);
            atomicAdd(&ssq [p * HID + col], s2);
        }
    }
    // ---- selected store: row & 15 == l4*4 + j  (m0, wr*64, m*16 are 16-aligned)
    bool sel[4];
    #pragma unroll
    for (int j = 0; j < 4; ++j) sel[j] = (proj[l4 * 4 + j] == p);
    #pragma unroll
    for (int m = 0; m < 4; ++m) {
        #pragma unroll
        for (int j = 0; j < 4; ++j) {
            if (sel[j]) {
                int row = m0 + wr * 64 + m * 16 + l4 * 4 + j;
                #pragma unroll
                for (int n = 0; n < 4; ++n) {
                    int col = n0 + wc * 64 + n * 16 + lc;
                    h_sel[(size_t)row * HID + col] = __float2bfloat16(acc[m][n][j]);
                }
            }
        }
    }
}

// ---------------------------------------------------------------------------
// Kernel 4: finalize BN -> scale/shift  s = gamma*rsqrt(var+eps), t = beta-mu*s
// ---------------------------------------------------------------------------
__global__ __launch_bounds__(256) void finalize_stats(
    const float* __restrict__ ssum, const float* __restrict__ ssq,
    const float* __restrict__ gamma, const float* __restrict__ beta,
    float* __restrict__ sbuf, float* __restrict__ tbuf)
{
    int i = blockIdx.x * 256 + threadIdx.x;            // < NPROJ*HID = 16384
    const float invN = 1.0f / (float)MROWS;
    float mu  = ssum[i] * invN;
    float var = ssq[i] * invN - mu * mu;
    float is  = rsqrtf(fmaxf(var, 0.0f) + 1e-5f);
    float sc  = gamma[i] * is;
    sbuf[i] = sc;
    tbuf[i] = beta[i] - mu * sc;
}

// ---------------------------------------------------------------------------
// Kernel 5: in-place BN-normalize + ReLU over h_sel (bf16), 8 elems/thread
// ---------------------------------------------------------------------------
__global__ __launch_bounds__(256) void bn_relu(
    __hip_bfloat16* __restrict__ h, const float* __restrict__ sbuf,
    const float* __restrict__ tbuf, const int* __restrict__ proj)
{
    size_t i = ((size_t)blockIdx.x * 256 + threadIdx.x) * 8;  // over 4096*4096
    int row = (int)(i >> 12);
    int k   = (int)(i & 4095);
    int p   = proj[row & 15];
    const float4* sp = (const float4*)(sbuf + (size_t)p * HID + k);
    const float4* tp = (const float4*)(tbuf + (size_t)p * HID + k);
    float4 s01 = sp[0], s23 = sp[1];
    float4 t01 = tp[0], t23 = tp[1];
    u16x8 hv = *(const u16x8*)(h + i);
    float sv[8] = {s01.x, s01.y, s01.z, s01.w, s23.x, s23.y, s23.z, s23.w};
    float tv[8] = {t01.x, t01.y, t01.z, t01.w, t23.x, t23.y, t23.z, t23.w};
    u16x8 ov;
    #pragma unroll
    for (int j = 0; j < 8; ++j) {
        float v = bf2f(hv[j]) * sv[j] + tv[j];
        ov[j] = f2bf(fmaxf(v, 0.0f));
    }
    *(u16x8*)(h + i) = ov;
}

// ---------------------------------------------------------------------------
// Kernel 6: GEMM2 (selected):  out[b,n,:] = relu_h[b*16+n,:] @ W2[proj[n]] + b2
// 64x64 tile, 4 waves 2x2 (each 32x32), K=4096.  grid (16 n, 4 bchunk, 4 cchunk)
// ---------------------------------------------------------------------------
__global__ __launch_bounds__(256) void gemm2(
    const __hip_bfloat16* __restrict__ Hn, const __hip_bfloat16* __restrict__ W2T,
    const int* __restrict__ proj, const float* __restrict__ b2,
    float* __restrict__ out)
{
    __shared__ __align__(16) __hip_bfloat16 As[64 * 32];
    __shared__ __align__(16) __hip_bfloat16 Bs[64 * 32];
    const int tid = threadIdx.x, lane = tid & 63, wid = tid >> 6;
    const int nmask = blockIdx.x;     // 0..15
    const int bc    = blockIdx.y;     // b chunk of 64
    const int ct    = blockIdx.z;     // out-col chunk of 64
    const int p = proj[nmask];
    const __hip_bfloat16* Bp = W2T + ((size_t)p * OUT + ct * 64) * HID;
    const int wr = wid >> 1, wc = wid & 1;
    const int l4 = lane >> 4, lc = lane & 15;

    f32x4 acc[2][2] = {};

    for (int k0 = 0; k0 < HID; k0 += 32) {
        __syncthreads();
        {
            int t = tid;                       // 256 threads cover 64 rows x 32 k
            int row = t >> 2, ko = (t & 3) * 8;
            GL16(Hn + ((size_t)(bc * 64 + row) * NMASK + nmask) * HID + k0 + ko,
                 &As[(wid * 64) * 8]);
            GL16(Bp + (size_t)row * HID + k0 + ko, &Bs[(wid * 64) * 8]);
        }
        __syncthreads();
        const bf16x8* Av = (const bf16x8*)As;
        const bf16x8* Bv = (const bf16x8*)Bs;
        bf16x8 a[2], b[2];
        a[0] = Av[(wr * 32 +      lc) * 4 + l4];
        a[1] = Av[(wr * 32 + 16 + lc) * 4 + l4];
        b[0] = Bv[(wc * 32 +      lc) * 4 + l4];
        b[1] = Bv[(wc * 32 + 16 + lc) * 4 + l4];
        #pragma unroll
        for (int m = 0; m < 2; ++m)
            #pragma unroll
            for (int n = 0; n < 2; ++n)
                acc[m][n] = __builtin_amdgcn_mfma_f32_16x16x32_bf16(a[m], b[n], acc[m][n], 0, 0, 0);
    }

    #pragma unroll
    for (int m = 0; m < 2; ++m)
        #pragma unroll
        for (int n = 0; n < 2; ++n)
            #pragma unroll
            for (int j = 0; j < 4; ++j) {
                int bb = bc * 64 + wr * 32 + m * 16 + l4 * 4 + j;
                int oc = ct * 64 + wc * 32 + n * 16 + lc;
                out[((size_t)bb * NMASK + nmask) * OUT + oc] = acc[m][n][j] + b2[p * OUT + oc];
            }
}

// ---------------------------------------------------------------------------
// Kernel 7: mask_ids (int) -> float tail of output
// ---------------------------------------------------------------------------
__global__ __launch_bounds__(256) void tail_ids(const int* __restrict__ mids,
                                                float* __restrict__ out)
{
    int i = blockIdx.x * 256 + threadIdx.x;   // < 4096
    out[(size_t)MROWS * OUT + i] = (float)mids[i];
}

// ---------------------------------------------------------------------------
extern "C" void kernel_launch(void* const* d_in, const int* in_sizes, int n_in,
                              void* d_out, int out_size, void* d_ws, size_t ws_size,
                              hipStream_t stream)
{
    const float* x     = (const float*)d_in[0];
    const float* masks = (const float*)d_in[1];
    const int*   proj  = (const int*)d_in[2];
    const int*   mids  = (const int*)d_in[3];
    const float* W1    = (const float*)d_in[4];
    // d_in[5] = b1: cancels exactly under training-mode BN -> unused
    const float* gamma = (const float*)d_in[6];
    const float* beta  = (const float*)d_in[7];
    const float* W2    = (const float*)d_in[8];
    const float* b2    = (const float*)d_in[9];
    float* out = (float*)d_out;

    char* ws = (char*)d_ws;
    // workspace layout (bytes), total ~73.7 MB
    __hip_bfloat16* pooled = (__hip_bfloat16*)(ws);                    //  6,291,456
    __hip_bfloat16* W1T    = (__hip_bfloat16*)(ws + 6291456);          // 25,165,824
    __hip_bfloat16* W2T    = (__hip_bfloat16*)(ws + 31457280);         //  8,388,608
    __hip_bfloat16* hsel   = (__hip_bfloat16*)(ws + 39845888);         // 33,554,432
    float*          ssum   = (float*)(ws + 73400320);                  //     65,536
    float*          ssq    = (float*)(ws + 73465856);                  //     65,536
    float*          sbuf   = (float*)(ws + 73531392);                  //     65,536
    float*          tbuf   = (float*)(ws + 73596928);                  //     65,536

    hipMemsetAsync(ssum, 0, 2 * NPROJ * HID * sizeof(float), stream);  // ssum+ssq

    pool_kernel<<<BS, 256, 0, stream>>>(x, masks, pooled);
    transpose_cvt<<<dim3(HID / 64, EMB / 64, NPROJ), 256, 0, stream>>>(W1, W1T, EMB, HID);
    transpose_cvt<<<dim3(OUT / 64, HID / 64, NPROJ), 256, 0, stream>>>(W2, W2T, HID, OUT);
    gemm1<<<dim3(HID / 128, MROWS / 128, NPROJ), 256, 0, stream>>>(pooled, W1T, proj, ssum, ssq, hsel);
    finalize_stats<<<(NPROJ * HID) / 256, 256, 0, stream>>>(ssum, ssq, gamma, beta, sbuf, tbuf);
    bn_relu<<<(MROWS * (HID / 8)) / 256, 256, 0, stream>>>(hsel, sbuf, tbuf, proj);
    gemm2<<<dim3(NMASK, BS / 64, OUT / 64), 256, 0, stream>>>(hsel, W2T, proj, b2, out);
    tail_ids<<<(BS * NMASK) / 256, 256, 0, stream>>>(mids, out);
}

// Round 3
// 280.731 us; speedup vs baseline: 1.2163x; 1.2163x over previous
//
#include <hip/hip_runtime.h>
#include <hip/hip_bf16.h>

// Problem constants
#define BS 256
#define EMB 768
#define HW 196          // 14*14
#define NMASK 16
#define HID 4096
#define OUT 256
#define NPROJ 4
#define MROWS 4096      // BS*NMASK

typedef __attribute__((ext_vector_type(8))) short bf16x8;
typedef __attribute__((ext_vector_type(4))) float f32x4;
typedef __attribute__((ext_vector_type(8))) unsigned short u16x8;

__device__ inline float bf2f(unsigned short u) {
    unsigned int x = ((unsigned int)u) << 16;
    return __builtin_bit_cast(float, x);
}

// async global->LDS, 16B per lane; lds base must be wave-uniform
#define GL16(gptr, lptr)                                                     \
    __builtin_amdgcn_global_load_lds(                                        \
        (const __attribute__((address_space(1))) void*)(gptr),               \
        (__attribute__((address_space(3))) void*)(lptr), 16, 0, 0)

// ---------------------------------------------------------------------------
// Kernel 1: masked mean pooling -> pooledG[row'=n*256+b][e]  (bf16)
// grid (EMB/64=12, BS=256), 256 threads
// ---------------------------------------------------------------------------
__global__ __launch_bounds__(256) void pool_kernel(
    const float* __restrict__ x, const float* __restrict__ masks,
    __hip_bfloat16* __restrict__ pooledG)
{
    __shared__ float msk[NMASK * HW];    // 12.25 KB
    __shared__ float xs[64 * HW];        // 50.2 KB (row stride 196 f = 784B, 16B aligned)
    __shared__ float inv[NMASK];
    const int ec = blockIdx.x, b = blockIdx.y, tid = threadIdx.x;

    const float4* mp4 = (const float4*)(masks + (size_t)b * NMASK * HW);
    float4* msk4 = (float4*)msk;
    for (int i = tid; i < NMASK * HW / 4; i += 256) msk4[i] = mp4[i];
    __syncthreads();
    // areas (tid<16) overlapped with x staging (independent of msk)
    if (tid < NMASK) {
        float a = 0.f;
        for (int hw = 0; hw < HW; ++hw) a += msk[tid * HW + hw];
        inv[tid] = 1.0f / fmaxf(a, 1.0f);
    }
    const float4* xp4 = (const float4*)(x + ((size_t)b * EMB + ec * 64) * HW);
    float4* xs4 = (float4*)xs;
    for (int i = tid; i < 64 * (HW / 4); i += 256) xs4[i] = xp4[i];
    __syncthreads();

    const int e_l = tid & 63, ng = tid >> 6;   // ng wave-uniform
    const float4* xrow = (const float4*)(xs + e_l * HW);
    const float4* m0 = (const float4*)(msk + (ng * 4 + 0) * HW);
    const float4* m1 = (const float4*)(msk + (ng * 4 + 1) * HW);
    const float4* m2 = (const float4*)(msk + (ng * 4 + 2) * HW);
    const float4* m3 = (const float4*)(msk + (ng * 4 + 3) * HW);
    float a0 = 0.f, a1 = 0.f, a2 = 0.f, a3 = 0.f;
    #pragma unroll 7
    for (int h4 = 0; h4 < HW / 4; ++h4) {
        float4 xv = xrow[h4];
        float4 v0 = m0[h4], v1 = m1[h4], v2 = m2[h4], v3 = m3[h4];
        a0 += xv.x * v0.x + xv.y * v0.y + xv.z * v0.z + xv.w * v0.w;
        a1 += xv.x * v1.x + xv.y * v1.y + xv.z * v1.z + xv.w * v1.w;
        a2 += xv.x * v2.x + xv.y * v2.y + xv.z * v2.z + xv.w * v2.w;
        a3 += xv.x * v3.x + xv.y * v3.y + xv.z * v3.z + xv.w * v3.w;
    }
    size_t base = (size_t)ec * 64 + e_l;
    pooledG[((size_t)(ng * 4 + 0) * 256 + b) * EMB + base] = __float2bfloat16(a0 * inv[ng * 4 + 0]);
    pooledG[((size_t)(ng * 4 + 1) * 256 + b) * EMB + base] = __float2bfloat16(a1 * inv[ng * 4 + 1]);
    pooledG[((size_t)(ng * 4 + 2) * 256 + b) * EMB + base] = __float2bfloat16(a2 * inv[ng * 4 + 2]);
    pooledG[((size_t)(ng * 4 + 3) * 256 + b) * EMB + base] = __float2bfloat16(a3 * inv[ng * 4 + 3]);
}

// ---------------------------------------------------------------------------
// Kernel 2: transpose + f32->bf16.  src [gz][R][C] f32 -> dst [gz][C][R] bf16
// ---------------------------------------------------------------------------
__global__ __launch_bounds__(256) void transpose_cvt(
    const float* __restrict__ src, __hip_bfloat16* __restrict__ dst, int R, int C)
{
    __shared__ float tile[64][65];
    const float* s = src + (size_t)blockIdx.z * R * C;
    __hip_bfloat16* d = dst + (size_t)blockIdx.z * R * C;
    const int c0 = blockIdx.x * 64, r0 = blockIdx.y * 64, tid = threadIdx.x;
    for (int i = tid; i < 4096; i += 256) {
        int r = i >> 6, c = i & 63;
        tile[r][c] = s[(size_t)(r0 + r) * C + c0 + c];
    }
    __syncthreads();
    for (int i = tid; i < 4096; i += 256) {
        int c = i >> 6, r = i & 63;
        d[(size_t)(c0 + c) * R + r0 + r] = __float2bfloat16(tile[r][c]);
    }
}

// ---------------------------------------------------------------------------
// Kernel 3: bf16 transpose pooledG [4096][768] -> pooledT [768][4096]
// grid (EMB/64=12, MROWS/64=64)
// ---------------------------------------------------------------------------
__global__ __launch_bounds__(256) void transpose_pg(
    const __hip_bfloat16* __restrict__ src, __hip_bfloat16* __restrict__ dst)
{
    __shared__ __hip_bfloat16 tile[64][65];
    const int c0 = blockIdx.x * 64, r0 = blockIdx.y * 64, tid = threadIdx.x;
    for (int i = tid; i < 4096; i += 256) {
        int r = i >> 6, c = i & 63;
        tile[r][c] = src[(size_t)(r0 + r) * EMB + c0 + c];
    }
    __syncthreads();
    for (int i = tid; i < 4096; i += 256) {
        int c = i >> 6, r = i & 63;
        dst[(size_t)(c0 + c) * MROWS + r0 + r] = tile[r][c];
    }
}

// ---------------------------------------------------------------------------
// Kernel 4: mp[e] = (1/4096) sum_r pooledT[e][r]
// ---------------------------------------------------------------------------
__global__ __launch_bounds__(256) void meanpool(
    const __hip_bfloat16* __restrict__ PT, float* __restrict__ mp)
{
    const int e = blockIdx.x, tid = threadIdx.x;
    const u16x8* p = (const u16x8*)(PT + (size_t)e * MROWS);
    u16x8 v1 = p[tid], v2 = p[tid + 256];
    float s = 0.f;
    #pragma unroll
    for (int j = 0; j < 8; ++j) s += bf2f((unsigned short)v1[j]) + bf2f((unsigned short)v2[j]);
    #pragma unroll
    for (int o = 1; o < 64; o <<= 1) s += __shfl_xor(s, o);
    __shared__ float wsum[4];
    if ((tid & 63) == 0) wsum[tid >> 6] = s;
    __syncthreads();
    if (tid == 0) mp[e] = (wsum[0] + wsum[1] + wsum[2] + wsum[3]) * (1.0f / 4096.0f);
}

// ---------------------------------------------------------------------------
// Kernel 5: C GEMM (split-K, atomic): Cf[i][j] += sum_k PT[i][k] PT[j][k]
// grid (6, 6, 8)  K-chunk = 512
// ---------------------------------------------------------------------------
__global__ __launch_bounds__(256) void cgemm(
    const __hip_bfloat16* __restrict__ PT, float* __restrict__ Cf)
{
    __shared__ __align__(16) __hip_bfloat16 As[128 * 32];
    __shared__ __align__(16) __hip_bfloat16 Bs[128 * 32];
    const int tid = threadIdx.x, lane = tid & 63, wid = tid >> 6;
    const int n0 = blockIdx.x * 128, m0 = blockIdx.y * 128, kbase = blockIdx.z * 512;
    const int wr = wid >> 1, wc = wid & 1;
    const int l4 = lane >> 4, lc = lane & 15;

    f32x4 acc[4][4] = {};
    for (int k0 = kbase; k0 < kbase + 512; k0 += 32) {
        __syncthreads();
        #pragma unroll
        for (int r = 0; r < 2; ++r) {
            int t = r * 256 + tid;
            int row = t >> 2, ko = (t & 3) * 8;
            GL16(PT + (size_t)(m0 + row) * MROWS + k0 + ko, &As[(r * 256 + wid * 64) * 8]);
        }
        #pragma unroll
        for (int r = 0; r < 2; ++r) {
            int t = r * 256 + tid;
            int row = t >> 2, ko = (t & 3) * 8;
            GL16(PT + (size_t)(n0 + row) * MROWS + k0 + ko, &Bs[(r * 256 + wid * 64) * 8]);
        }
        __syncthreads();
        const bf16x8* Av = (const bf16x8*)As;
        const bf16x8* Bv = (const bf16x8*)Bs;
        bf16x8 a[4], b[4];
        #pragma unroll
        for (int m = 0; m < 4; ++m) a[m] = Av[(wr * 64 + m * 16 + lc) * 4 + l4];
        #pragma unroll
        for (int n = 0; n < 4; ++n) b[n] = Bv[(wc * 64 + n * 16 + lc) * 4 + l4];
        #pragma unroll
        for (int m = 0; m < 4; ++m)
            #pragma unroll
            for (int n = 0; n < 4; ++n)
                acc[m][n] = __builtin_amdgcn_mfma_f32_16x16x32_bf16(a[m], b[n], acc[m][n], 0, 0, 0);
    }
    #pragma unroll
    for (int m = 0; m < 4; ++m)
        #pragma unroll
        for (int n = 0; n < 4; ++n)
            #pragma unroll
            for (int j = 0; j < 4; ++j) {
                int row = m0 + wr * 64 + m * 16 + l4 * 4 + j;
                int col = n0 + wc * 64 + n * 16 + lc;
                atomicAdd(&Cf[(size_t)row * EMB + col], acc[m][n][j]);
            }
}

// ---------------------------------------------------------------------------
// Kernel 6: Cf f32 -> Cbf bf16 with 1/N fold
// ---------------------------------------------------------------------------
__global__ __launch_bounds__(256) void cvt_c(
    const float* __restrict__ Cf, __hip_bfloat16* __restrict__ Cbf)
{
    int i = (blockIdx.x * 256 + threadIdx.x) * 4;   // < 768*768
    float4 v = *(const float4*)(Cf + i);
    const float s = 1.0f / 4096.0f;
    Cbf[i + 0] = __float2bfloat16(v.x * s);
    Cbf[i + 1] = __float2bfloat16(v.y * s);
    Cbf[i + 2] = __float2bfloat16(v.z * s);
    Cbf[i + 3] = __float2bfloat16(v.w * s);
}

// ---------------------------------------------------------------------------
// Kernel 7: U GEMM + fused stats:  for p:  Ublk = W1T[p] @ Cbf  (M=4096 j,
// N=768 e, K=768), epilogue accumulates Eh2[p][j] += sum_e U*w, Mu[p][j] += mp.w
// grid (6, 32, 4)
// ---------------------------------------------------------------------------
__global__ __launch_bounds__(256) void ugemm(
    const __hip_bfloat16* __restrict__ W1T, const __hip_bfloat16* __restrict__ Cbf,
    const float* __restrict__ mp,
    float* __restrict__ Eh2, float* __restrict__ Mu)
{
    __shared__ __align__(16) __hip_bfloat16 As[128 * 32];
    __shared__ __align__(16) __hip_bfloat16 Bs[128 * 32];
    const int tid = threadIdx.x, lane = tid & 63, wid = tid >> 6;
    const int n0 = blockIdx.x * 128, m0 = blockIdx.y * 128, p = blockIdx.z;
    const __hip_bfloat16* Ap = W1T + (size_t)p * HID * EMB;
    const int wr = wid >> 1, wc = wid & 1;
    const int l4 = lane >> 4, lc = lane & 15;

    f32x4 acc[4][4] = {};
    for (int k0 = 0; k0 < EMB; k0 += 32) {
        __syncthreads();
        #pragma unroll
        for (int r = 0; r < 2; ++r) {
            int t = r * 256 + tid;
            int row = t >> 2, ko = (t & 3) * 8;
            GL16(Ap + (size_t)(m0 + row) * EMB + k0 + ko, &As[(r * 256 + wid * 64) * 8]);
        }
        #pragma unroll
        for (int r = 0; r < 2; ++r) {
            int t = r * 256 + tid;
            int row = t >> 2, ko = (t & 3) * 8;
            GL16(Cbf + (size_t)(n0 + row) * EMB + k0 + ko, &Bs[(r * 256 + wid * 64) * 8]);
        }
        __syncthreads();
        const bf16x8* Av = (const bf16x8*)As;
        const bf16x8* Bv = (const bf16x8*)Bs;
        bf16x8 a[4], b[4];
        #pragma unroll
        for (int m = 0; m < 4; ++m) a[m] = Av[(wr * 64 + m * 16 + lc) * 4 + l4];
        #pragma unroll
        for (int n = 0; n < 4; ++n) b[n] = Bv[(wc * 64 + n * 16 + lc) * 4 + l4];
        #pragma unroll
        for (int m = 0; m < 4; ++m)
            #pragma unroll
            for (int n = 0; n < 4; ++n)
                acc[m][n] = __builtin_amdgcn_mfma_f32_16x16x32_bf16(a[m], b[n], acc[m][n], 0, 0, 0);
    }

    // fused row-dot: Eh2[p][row] += sum_col acc*W1T[p][row][col]; Mu likewise
    float mpv[4];
    #pragma unroll
    for (int n = 0; n < 4; ++n) mpv[n] = mp[n0 + wc * 64 + n * 16 + lc];
    #pragma unroll
    for (int m = 0; m < 4; ++m) {
        #pragma unroll
        for (int j = 0; j < 4; ++j) {
            int row = m0 + wr * 64 + m * 16 + l4 * 4 + j;
            const __hip_bfloat16* wrow = Ap + (size_t)row * EMB;
            float e2 = 0.f, mu = 0.f;
            #pragma unroll
            for (int n = 0; n < 4; ++n) {
                int col = n0 + wc * 64 + n * 16 + lc;
                float wv = bf2f(__builtin_bit_cast(unsigned short, wrow[col]));
                e2 += acc[m][n][j] * wv;
                mu += mpv[n] * wv;
            }
            e2 += __shfl_xor(e2, 1); e2 += __shfl_xor(e2, 2);
            e2 += __shfl_xor(e2, 4); e2 += __shfl_xor(e2, 8);
            mu += __shfl_xor(mu, 1); mu += __shfl_xor(mu, 2);
            mu += __shfl_xor(mu, 4); mu += __shfl_xor(mu, 8);
            if (lc == 0) {
                atomicAdd(&Eh2[p * HID + row], e2);
                atomicAdd(&Mu [p * HID + row], mu);
            }
        }
    }
}

// ---------------------------------------------------------------------------
// Kernel 8: finalize  s = gamma*rsqrt(var+eps), t = beta - mu*s
// ---------------------------------------------------------------------------
__global__ __launch_bounds__(256) void finalize(
    const float* __restrict__ Eh2, const float* __restrict__ Mu,
    const float* __restrict__ gamma, const float* __restrict__ beta,
    float* __restrict__ sbuf, float* __restrict__ tbuf)
{
    int i = blockIdx.x * 256 + threadIdx.x;            // < 16384
    float mu  = Mu[i];
    float var = Eh2[i] - mu * mu;
    float is  = rsqrtf(fmaxf(var, 0.0f) + 1e-5f);
    float sc  = gamma[i] * is;
    sbuf[i] = sc;
    tbuf[i] = beta[i] - mu * sc;
}

// ---------------------------------------------------------------------------
// Kernel 9: selected GEMM1 + fused BN+ReLU:
//   hrelu[row'] = relu( (pooledG[row'] @ W1[proj[row'>>8]]) * s + t )
// grid (HID/128=32, MROWS/128=32)
// ---------------------------------------------------------------------------
__global__ __launch_bounds__(256) void gemm1_sel(
    const __hip_bfloat16* __restrict__ A, const __hip_bfloat16* __restrict__ W1T,
    const int* __restrict__ proj,
    const float* __restrict__ sbuf, const float* __restrict__ tbuf,
    __hip_bfloat16* __restrict__ hrelu)
{
    __shared__ __align__(16) __hip_bfloat16 As[128 * 32];
    __shared__ __align__(16) __hip_bfloat16 Bs[128 * 32];
    const int tid = threadIdx.x, lane = tid & 63, wid = tid >> 6;
    const int n0 = blockIdx.x * 128, m0 = blockIdx.y * 128;
    const int p = proj[blockIdx.y >> 1];
    const __hip_bfloat16* Bp = W1T + (size_t)p * HID * EMB;
    const int wr = wid >> 1, wc = wid & 1;
    const int l4 = lane >> 4, lc = lane & 15;

    f32x4 acc[4][4] = {};
    for (int k0 = 0; k0 < EMB; k0 += 32) {
        __syncthreads();
        #pragma unroll
        for (int r = 0; r < 2; ++r) {
            int t = r * 256 + tid;
            int row = t >> 2, ko = (t & 3) * 8;
            GL16(A + (size_t)(m0 + row) * EMB + k0 + ko, &As[(r * 256 + wid * 64) * 8]);
        }
        #pragma unroll
        for (int r = 0; r < 2; ++r) {
            int t = r * 256 + tid;
            int row = t >> 2, ko = (t & 3) * 8;
            GL16(Bp + (size_t)(n0 + row) * EMB + k0 + ko, &Bs[(r * 256 + wid * 64) * 8]);
        }
        __syncthreads();
        const bf16x8* Av = (const bf16x8*)As;
        const bf16x8* Bv = (const bf16x8*)Bs;
        bf16x8 a[4], b[4];
        #pragma unroll
        for (int m = 0; m < 4; ++m) a[m] = Av[(wr * 64 + m * 16 + lc) * 4 + l4];
        #pragma unroll
        for (int n = 0; n < 4; ++n) b[n] = Bv[(wc * 64 + n * 16 + lc) * 4 + l4];
        #pragma unroll
        for (int m = 0; m < 4; ++m)
            #pragma unroll
            for (int n = 0; n < 4; ++n)
                acc[m][n] = __builtin_amdgcn_mfma_f32_16x16x32_bf16(a[m], b[n], acc[m][n], 0, 0, 0);
    }

    #pragma unroll
    for (int n = 0; n < 4; ++n) {
        int col = n0 + wc * 64 + n * 16 + lc;
        float s = sbuf[p * HID + col];
        float t = tbuf[p * HID + col];
        #pragma unroll
        for (int m = 0; m < 4; ++m)
            #pragma unroll
            for (int j = 0; j < 4; ++j) {
                int row = m0 + wr * 64 + m * 16 + l4 * 4 + j;
                float v = fmaxf(acc[m][n][j] * s + t, 0.0f);
                hrelu[(size_t)row * HID + col] = __float2bfloat16(v);
            }
    }
}

// ---------------------------------------------------------------------------
// Kernel 10: GEMM2:  out[b,n,:] = hrelu[n*256+b,:] @ W2[proj[n]] + b2
// grid (16, 4, 4)
// ---------------------------------------------------------------------------
__global__ __launch_bounds__(256) void gemm2(
    const __hip_bfloat16* __restrict__ Hn, const __hip_bfloat16* __restrict__ W2T,
    const int* __restrict__ proj, const float* __restrict__ b2,
    float* __restrict__ out)
{
    __shared__ __align__(16) __hip_bfloat16 As[64 * 32];
    __shared__ __align__(16) __hip_bfloat16 Bs[64 * 32];
    const int tid = threadIdx.x, lane = tid & 63, wid = tid >> 6;
    const int nmask = blockIdx.x;
    const int bc    = blockIdx.y;
    const int ct    = blockIdx.z;
    const int p = proj[nmask];
    const __hip_bfloat16* Ap = Hn + (size_t)(nmask * 256 + bc * 64) * HID;
    const __hip_bfloat16* Bp = W2T + ((size_t)p * OUT + ct * 64) * HID;
    const int wr = wid >> 1, wc = wid & 1;
    const int l4 = lane >> 4, lc = lane & 15;

    f32x4 acc[2][2] = {};
    for (int k0 = 0; k0 < HID; k0 += 32) {
        __syncthreads();
        {
            int row = tid >> 2, ko = (tid & 3) * 8;
            GL16(Ap + (size_t)row * HID + k0 + ko, &As[(wid * 64) * 8]);
            GL16(Bp + (size_t)row * HID + k0 + ko, &Bs[(wid * 64) * 8]);
        }
        __syncthreads();
        const bf16x8* Av = (const bf16x8*)As;
        const bf16x8* Bv = (const bf16x8*)Bs;
        bf16x8 a[2], b[2];
        a[0] = Av[(wr * 32 +      lc) * 4 + l4];
        a[1] = Av[(wr * 32 + 16 + lc) * 4 + l4];
        b[0] = Bv[(wc * 32 +      lc) * 4 + l4];
        b[1] = Bv[(wc * 32 + 16 + lc) * 4 + l4];
        #pragma unroll
        for (int m = 0; m < 2; ++m)
            #pragma unroll
            for (int n = 0; n < 2; ++n)
                acc[m][n] = __builtin_amdgcn_mfma_f32_16x16x32_bf16(a[m], b[n], acc[m][n], 0, 0, 0);
    }

    #pragma unroll
    for (int m = 0; m < 2; ++m)
        #pragma unroll
        for (int n = 0; n < 2; ++n)
            #pragma unroll
            for (int j = 0; j < 4; ++j) {
                int bb = bc * 64 + wr * 32 + m * 16 + l4 * 4 + j;
                int oc = ct * 64 + wc * 32 + n * 16 + lc;
                out[((size_t)bb * NMASK + nmask) * OUT + oc] = acc[m][n][j] + b2[p * OUT + oc];
            }
}

// ---------------------------------------------------------------------------
// Kernel 11: mask_ids (int) -> float tail of output
// ---------------------------------------------------------------------------
__global__ __launch_bounds__(256) void tail_ids(const int* __restrict__ mids,
                                                float* __restrict__ out)
{
    int i = blockIdx.x * 256 + threadIdx.x;   // < 4096
    out[(size_t)MROWS * OUT + i] = (float)mids[i];
}

// ---------------------------------------------------------------------------
extern "C" void kernel_launch(void* const* d_in, const int* in_sizes, int n_in,
                              void* d_out, int out_size, void* d_ws, size_t ws_size,
                              hipStream_t stream)
{
    const float* x     = (const float*)d_in[0];
    const float* masks = (const float*)d_in[1];
    const int*   proj  = (const int*)d_in[2];
    const int*   mids  = (const int*)d_in[3];
    const float* W1    = (const float*)d_in[4];
    // d_in[5] = b1: cancels exactly under training-mode BN -> unused
    const float* gamma = (const float*)d_in[6];
    const float* beta  = (const float*)d_in[7];
    const float* W2    = (const float*)d_in[8];
    const float* b2    = (const float*)d_in[9];
    float* out = (float*)d_out;

    char* ws = (char*)d_ws;
    // layout (bytes), total 73,665,536 (<= 73.7MB proven working)
    __hip_bfloat16* pooledG = (__hip_bfloat16*)(ws);                   //  6,291,456
    __hip_bfloat16* W1T     = (__hip_bfloat16*)(ws + 6291456);         // 25,165,824
    __hip_bfloat16* W2T     = (__hip_bfloat16*)(ws + 31457280);        //  8,388,608
    float*          mp      = (float*)(ws + 39845888);                 //      3,072
    float*          Eh2     = (float*)(ws + 39848960);                 //     65,536
    float*          Mu      = (float*)(ws + 39914496);                 //     65,536
    float*          sbuf    = (float*)(ws + 39980032);                 //     65,536
    float*          tbuf    = (float*)(ws + 40045568);                 //     65,536
    // region R (aliased lifetimes):
    char* R = ws + 40111104;
    __hip_bfloat16* pooledT = (__hip_bfloat16*)(R);                    //  6,291,456
    float*          Cf      = (float*)(R + 6291456);                   //  2,359,296
    __hip_bfloat16* Cbf     = (__hip_bfloat16*)(R + 8650752);          //  1,179,648
    __hip_bfloat16* hrelu   = (__hip_bfloat16*)(R);                    // 33,554,432 (after Cbf consumed)

    hipMemsetAsync(Eh2, 0, 2 * NPROJ * HID * sizeof(float), stream);   // Eh2+Mu
    hipMemsetAsync(Cf, 0, EMB * EMB * sizeof(float), stream);

    pool_kernel<<<dim3(EMB / 64, BS), 256, 0, stream>>>(x, masks, pooledG);
    transpose_cvt<<<dim3(HID / 64, EMB / 64, NPROJ), 256, 0, stream>>>(W1, W1T, EMB, HID);
    transpose_cvt<<<dim3(OUT / 64, HID / 64, NPROJ), 256, 0, stream>>>(W2, W2T, HID, OUT);
    transpose_pg<<<dim3(EMB / 64, MROWS / 64), 256, 0, stream>>>(pooledG, pooledT);
    meanpool<<<EMB, 256, 0, stream>>>(pooledT, mp);
    cgemm<<<dim3(6, 6, 8), 256, 0, stream>>>(pooledT, Cf);
    cvt_c<<<(EMB * EMB) / 1024, 256, 0, stream>>>(Cf, Cbf);
    ugemm<<<dim3(6, 32, 4), 256, 0, stream>>>(W1T, Cbf, mp, Eh2, Mu);
    finalize<<<(NPROJ * HID) / 256, 256, 0, stream>>>(Eh2, Mu, gamma, beta, sbuf, tbuf);
    gemm1_sel<<<dim3(HID / 128, MROWS / 128), 256, 0, stream>>>(pooledG, W1T, proj, sbuf, tbuf, hrelu);
    gemm2<<<dim3(NMASK, BS / 64, OUT / 64), 256, 0, stream>>>(hrelu, W2T, proj, b2, out);
    tail_ids<<<(BS * NMASK) / 256, 256, 0, stream>>>(mids, out);
}

// Round 4
// 232.661 us; speedup vs baseline: 1.4676x; 1.2066x over previous
//
#include <hip/hip_runtime.h>
#include <hip/hip_bf16.h>

// Problem constants
#define BS 256
#define EMB 768
#define HW 196          // 14*14
#define NMASK 16
#define HID 4096
#define OUT 256
#define NPROJ 4
#define MROWS 4096      // BS*NMASK

typedef __attribute__((ext_vector_type(8))) short bf16x8;
typedef __attribute__((ext_vector_type(4))) float f32x4;
typedef __attribute__((ext_vector_type(8))) unsigned short u16x8;

__device__ inline float bf2f(unsigned short u) {
    unsigned int x = ((unsigned int)u) << 16;
    return __builtin_bit_cast(float, x);
}
__device__ inline short f2bfs(float f) {
    return __builtin_bit_cast(short, __float2bfloat16(f));
}

// async global->LDS, 16B per lane; lds base must be wave-uniform
#define GL16(gptr, lptr)                                                     \
    __builtin_amdgcn_global_load_lds(                                        \
        (const __attribute__((address_space(1))) void*)(gptr),               \
        (__attribute__((address_space(3))) void*)(lptr), 16, 0, 0)

// ---------------------------------------------------------------------------
// Kernel 1: masked mean pooling via MFMA.
//   pooled[b][m][e] = inv_area[m] * sum_hw masks[b][m][hw] * x[b][e][hw]
// A (16 x K=196->224) = masks (bf16, zero-padded), B^T (768 x 196) = x rows.
// grid (4, 256): blockIdx.x = e-chunk of 192, blockIdx.y = b. 4 waves x 48 e.
// ---------------------------------------------------------------------------
__global__ __launch_bounds__(256) void pool_mfma(
    const float* __restrict__ x, const float* __restrict__ masks,
    __hip_bfloat16* __restrict__ pooledG)
{
    __shared__ __align__(16) short afr[7 * 64 * 8];   // A-fragments, 7 KB
    __shared__ float inv[NMASK];
    const int ec = blockIdx.x, b = blockIdx.y, tid = threadIdx.x;
    const float* mb = masks + (size_t)b * NMASK * HW;

    // stage A-fragments: slot s=(kc*64+l): m=l&15, k=kc*32+(l>>4)*8 (+j)
    for (int s = tid; s < 7 * 64; s += 256) {
        int m = s & 15, kb = ((s >> 4) & 3) * 8 + (s >> 6) * 32;
        short v[8];
        #pragma unroll
        for (int j = 0; j < 8; ++j) {
            int kk = kb + j;
            v[j] = (kk < HW) ? f2bfs(mb[m * HW + kk]) : (short)0;
        }
        #pragma unroll
        for (int j = 0; j < 8; ++j) afr[s * 8 + j] = v[j];
    }
    // areas: wave 3, 4 lanes per mask
    if (tid >= 192) {
        int l = tid - 192, m = l >> 2, q = l & 3;
        float a = 0.f;
        for (int hw = q; hw < HW; hw += 4) a += mb[m * HW + hw];
        a += __shfl_xor(a, 1);
        a += __shfl_xor(a, 2);
        if (q == 0) inv[m] = 1.0f / fmaxf(a, 1.0f);
    }
    __syncthreads();

    const int lane = tid & 63, w = tid >> 6;
    const int lc = lane & 15, l4 = lane >> 4;
    const int ebase = ec * 192 + w * 48;
    const bf16x8* afv = (const bf16x8*)afr;
    f32x4 acc[3] = {};

    const float* xb0 = x + ((size_t)b * EMB + ebase + lc) * HW;

    for (int kc = 0; kc < 6; ++kc) {
        bf16x8 af = afv[kc * 64 + lane];
        float4 u[3][2];
        #pragma unroll
        for (int t = 0; t < 3; ++t) {
            const float* xr = xb0 + (size_t)(t * 16) * HW + kc * 32 + l4 * 8;
            u[t][0] = *(const float4*)(xr);
            u[t][1] = *(const float4*)(xr + 4);
        }
        #pragma unroll
        for (int t = 0; t < 3; ++t) {
            bf16x8 bf;
            bf[0] = f2bfs(u[t][0].x); bf[1] = f2bfs(u[t][0].y);
            bf[2] = f2bfs(u[t][0].z); bf[3] = f2bfs(u[t][0].w);
            bf[4] = f2bfs(u[t][1].x); bf[5] = f2bfs(u[t][1].y);
            bf[6] = f2bfs(u[t][1].z); bf[7] = f2bfs(u[t][1].w);
            acc[t] = __builtin_amdgcn_mfma_f32_16x16x32_bf16(af, bf, acc[t], 0, 0, 0);
        }
    }
    {   // tail K-chunk: k=192..196 valid (l4==0 only), rest zero (A also zero)
        bf16x8 af = afv[6 * 64 + lane];
        #pragma unroll
        for (int t = 0; t < 3; ++t) {
            bf16x8 bf = {};
            if (l4 == 0) {
                float4 u0 = *(const float4*)(xb0 + (size_t)(t * 16) * HW + 192);
                bf[0] = f2bfs(u0.x); bf[1] = f2bfs(u0.y);
                bf[2] = f2bfs(u0.z); bf[3] = f2bfs(u0.w);
            }
            acc[t] = __builtin_amdgcn_mfma_f32_16x16x32_bf16(af, bf, acc[t], 0, 0, 0);
        }
    }

    // epilogue: D col(lane&15)=e, row((lane>>4)*4+j)=m ; scale by inv[m]
    #pragma unroll
    for (int t = 0; t < 3; ++t) {
        int e = ebase + t * 16 + lc;
        #pragma unroll
        for (int j = 0; j < 4; ++j) {
            int m = l4 * 4 + j;
            pooledG[((size_t)m * 256 + b) * EMB + e] =
                __float2bfloat16(acc[t][j] * inv[m]);
        }
    }
}

// ---------------------------------------------------------------------------
// Kernel 2: transpose + f32->bf16.  src [gz][R][C] f32 -> dst [gz][C][R] bf16
// ---------------------------------------------------------------------------
__global__ __launch_bounds__(256) void transpose_cvt(
    const float* __restrict__ src, __hip_bfloat16* __restrict__ dst, int R, int C)
{
    __shared__ float tile[64][65];
    const float* s = src + (size_t)blockIdx.z * R * C;
    __hip_bfloat16* d = dst + (size_t)blockIdx.z * R * C;
    const int c0 = blockIdx.x * 64, r0 = blockIdx.y * 64, tid = threadIdx.x;
    for (int i = tid; i < 4096; i += 256) {
        int r = i >> 6, c = i & 63;
        tile[r][c] = s[(size_t)(r0 + r) * C + c0 + c];
    }
    __syncthreads();
    for (int i = tid; i < 4096; i += 256) {
        int c = i >> 6, r = i & 63;
        d[(size_t)(c0 + c) * R + r0 + r] = __float2bfloat16(tile[r][c]);
    }
}

// ---------------------------------------------------------------------------
// Kernel 3: bf16 transpose pooledG [4096][768] -> pooledT [768][4096]
// ---------------------------------------------------------------------------
__global__ __launch_bounds__(256) void transpose_pg(
    const __hip_bfloat16* __restrict__ src, __hip_bfloat16* __restrict__ dst)
{
    __shared__ __hip_bfloat16 tile[64][65];
    const int c0 = blockIdx.x * 64, r0 = blockIdx.y * 64, tid = threadIdx.x;
    for (int i = tid; i < 4096; i += 256) {
        int r = i >> 6, c = i & 63;
        tile[r][c] = src[(size_t)(r0 + r) * EMB + c0 + c];
    }
    __syncthreads();
    for (int i = tid; i < 4096; i += 256) {
        int c = i >> 6, r = i & 63;
        dst[(size_t)(c0 + c) * MROWS + r0 + r] = tile[r][c];
    }
}

// ---------------------------------------------------------------------------
// Kernel 4: mp[e] = (1/4096) sum_r pooledT[e][r]
// ---------------------------------------------------------------------------
__global__ __launch_bounds__(256) void meanpool(
    const __hip_bfloat16* __restrict__ PT, float* __restrict__ mp)
{
    const int e = blockIdx.x, tid = threadIdx.x;
    const u16x8* p = (const u16x8*)(PT + (size_t)e * MROWS);
    u16x8 v1 = p[tid], v2 = p[tid + 256];
    float s = 0.f;
    #pragma unroll
    for (int j = 0; j < 8; ++j) s += bf2f((unsigned short)v1[j]) + bf2f((unsigned short)v2[j]);
    #pragma unroll
    for (int o = 1; o < 64; o <<= 1) s += __shfl_xor(s, o);
    __shared__ float wsum[4];
    if ((tid & 63) == 0) wsum[tid >> 6] = s;
    __syncthreads();
    if (tid == 0) mp[e] = (wsum[0] + wsum[1] + wsum[2] + wsum[3]) * (1.0f / 4096.0f);
}

// ---------------------------------------------------------------------------
// Kernel 5: C GEMM (split-K, atomic): Cf[i][j] += sum_k PT[i][k] PT[j][k]
// grid (6, 6, 8)  K-chunk = 512
// ---------------------------------------------------------------------------
__global__ __launch_bounds__(256) void cgemm(
    const __hip_bfloat16* __restrict__ PT, float* __restrict__ Cf)
{
    __shared__ __align__(16) __hip_bfloat16 As[128 * 32];
    __shared__ __align__(16) __hip_bfloat16 Bs[128 * 32];
    const int tid = threadIdx.x, lane = tid & 63, wid = tid >> 6;
    const int n0 = blockIdx.x * 128, m0 = blockIdx.y * 128, kbase = blockIdx.z * 512;
    const int wr = wid >> 1, wc = wid & 1;
    const int l4 = lane >> 4, lc = lane & 15;

    f32x4 acc[4][4] = {};
    for (int k0 = kbase; k0 < kbase + 512; k0 += 32) {
        __syncthreads();
        #pragma unroll
        for (int r = 0; r < 2; ++r) {
            int t = r * 256 + tid;
            int row = t >> 2, ko = (t & 3) * 8;
            GL16(PT + (size_t)(m0 + row) * MROWS + k0 + ko, &As[(r * 256 + wid * 64) * 8]);
        }
        #pragma unroll
        for (int r = 0; r < 2; ++r) {
            int t = r * 256 + tid;
            int row = t >> 2, ko = (t & 3) * 8;
            GL16(PT + (size_t)(n0 + row) * MROWS + k0 + ko, &Bs[(r * 256 + wid * 64) * 8]);
        }
        __syncthreads();
        const bf16x8* Av = (const bf16x8*)As;
        const bf16x8* Bv = (const bf16x8*)Bs;
        bf16x8 a[4], b[4];
        #pragma unroll
        for (int m = 0; m < 4; ++m) a[m] = Av[(wr * 64 + m * 16 + lc) * 4 + l4];
        #pragma unroll
        for (int n = 0; n < 4; ++n) b[n] = Bv[(wc * 64 + n * 16 + lc) * 4 + l4];
        #pragma unroll
        for (int m = 0; m < 4; ++m)
            #pragma unroll
            for (int n = 0; n < 4; ++n)
                acc[m][n] = __builtin_amdgcn_mfma_f32_16x16x32_bf16(a[m], b[n], acc[m][n], 0, 0, 0);
    }
    #pragma unroll
    for (int m = 0; m < 4; ++m)
        #pragma unroll
        for (int n = 0; n < 4; ++n)
            #pragma unroll
            for (int j = 0; j < 4; ++j) {
                int row = m0 + wr * 64 + m * 16 + l4 * 4 + j;
                int col = n0 + wc * 64 + n * 16 + lc;
                atomicAdd(&Cf[(size_t)row * EMB + col], acc[m][n][j]);
            }
}

// ---------------------------------------------------------------------------
// Kernel 6: Cf f32 -> Cbf bf16 with 1/N fold
// ---------------------------------------------------------------------------
__global__ __launch_bounds__(256) void cvt_c(
    const float* __restrict__ Cf, __hip_bfloat16* __restrict__ Cbf)
{
    int i = (blockIdx.x * 256 + threadIdx.x) * 4;   // < 768*768
    float4 v = *(const float4*)(Cf + i);
    const float s = 1.0f / 4096.0f;
    Cbf[i + 0] = __float2bfloat16(v.x * s);
    Cbf[i + 1] = __float2bfloat16(v.y * s);
    Cbf[i + 2] = __float2bfloat16(v.z * s);
    Cbf[i + 3] = __float2bfloat16(v.w * s);
}

// ---------------------------------------------------------------------------
// Kernel 7: U GEMM + fused stats:  Ublk = W1T[p] @ Cbf; epilogue row-dots
// Eh2[p][j] += sum_e U*w, Mu[p][j] += mp.w    grid (6, 32, 4)
// ---------------------------------------------------------------------------
__global__ __launch_bounds__(256) void ugemm(
    const __hip_bfloat16* __restrict__ W1T, const __hip_bfloat16* __restrict__ Cbf,
    const float* __restrict__ mp,
    float* __restrict__ Eh2, float* __restrict__ Mu)
{
    __shared__ __align__(16) __hip_bfloat16 As[128 * 32];
    __shared__ __align__(16) __hip_bfloat16 Bs[128 * 32];
    const int tid = threadIdx.x, lane = tid & 63, wid = tid >> 6;
    const int n0 = blockIdx.x * 128, m0 = blockIdx.y * 128, p = blockIdx.z;
    const __hip_bfloat16* Ap = W1T + (size_t)p * HID * EMB;
    const int wr = wid >> 1, wc = wid & 1;
    const int l4 = lane >> 4, lc = lane & 15;

    f32x4 acc[4][4] = {};
    for (int k0 = 0; k0 < EMB; k0 += 32) {
        __syncthreads();
        #pragma unroll
        for (int r = 0; r < 2; ++r) {
            int t = r * 256 + tid;
            int row = t >> 2, ko = (t & 3) * 8;
            GL16(Ap + (size_t)(m0 + row) * EMB + k0 + ko, &As[(r * 256 + wid * 64) * 8]);
        }
        #pragma unroll
        for (int r = 0; r < 2; ++r) {
            int t = r * 256 + tid;
            int row = t >> 2, ko = (t & 3) * 8;
            GL16(Cbf + (size_t)(n0 + row) * EMB + k0 + ko, &Bs[(r * 256 + wid * 64) * 8]);
        }
        __syncthreads();
        const bf16x8* Av = (const bf16x8*)As;
        const bf16x8* Bv = (const bf16x8*)Bs;
        bf16x8 a[4], b[4];
        #pragma unroll
        for (int m = 0; m < 4; ++m) a[m] = Av[(wr * 64 + m * 16 + lc) * 4 + l4];
        #pragma unroll
        for (int n = 0; n < 4; ++n) b[n] = Bv[(wc * 64 + n * 16 + lc) * 4 + l4];
        #pragma unroll
        for (int m = 0; m < 4; ++m)
            #pragma unroll
            for (int n = 0; n < 4; ++n)
                acc[m][n] = __builtin_amdgcn_mfma_f32_16x16x32_bf16(a[m], b[n], acc[m][n], 0, 0, 0);
    }

    float mpv[4];
    #pragma unroll
    for (int n = 0; n < 4; ++n) mpv[n] = mp[n0 + wc * 64 + n * 16 + lc];
    #pragma unroll
    for (int m = 0; m < 4; ++m) {
        #pragma unroll
        for (int j = 0; j < 4; ++j) {
            int row = m0 + wr * 64 + m * 16 + l4 * 4 + j;
            const __hip_bfloat16* wrow = Ap + (size_t)row * EMB;
            float e2 = 0.f, mu = 0.f;
            #pragma unroll
            for (int n = 0; n < 4; ++n) {
                int col = n0 + wc * 64 + n * 16 + lc;
                float wv = bf2f(__builtin_bit_cast(unsigned short, wrow[col]));
                e2 += acc[m][n][j] * wv;
                mu += mpv[n] * wv;
            }
            e2 += __shfl_xor(e2, 1); e2 += __shfl_xor(e2, 2);
            e2 += __shfl_xor(e2, 4); e2 += __shfl_xor(e2, 8);
            mu += __shfl_xor(mu, 1); mu += __shfl_xor(mu, 2);
            mu += __shfl_xor(mu, 4); mu += __shfl_xor(mu, 8);
            if (lc == 0) {
                atomicAdd(&Eh2[p * HID + row], e2);
                atomicAdd(&Mu [p * HID + row], mu);
            }
        }
    }
}

// ---------------------------------------------------------------------------
// Kernel 8: finalize  s = gamma*rsqrt(var+eps), t = beta - mu*s
// ---------------------------------------------------------------------------
__global__ __launch_bounds__(256) void finalize(
    const float* __restrict__ Eh2, const float* __restrict__ Mu,
    const float* __restrict__ gamma, const float* __restrict__ beta,
    float* __restrict__ sbuf, float* __restrict__ tbuf)
{
    int i = blockIdx.x * 256 + threadIdx.x;            // < 16384
    float mu  = Mu[i];
    float var = Eh2[i] - mu * mu;
    float is  = rsqrtf(fmaxf(var, 0.0f) + 1e-5f);
    float sc  = gamma[i] * is;
    sbuf[i] = sc;
    tbuf[i] = beta[i] - mu * sc;
}

// ---------------------------------------------------------------------------
// Kernel 9: selected GEMM1 + fused BN+ReLU
// grid (HID/128=32, MROWS/128=32)
// ---------------------------------------------------------------------------
__global__ __launch_bounds__(256) void gemm1_sel(
    const __hip_bfloat16* __restrict__ A, const __hip_bfloat16* __restrict__ W1T,
    const int* __restrict__ proj,
    const float* __restrict__ sbuf, const float* __restrict__ tbuf,
    __hip_bfloat16* __restrict__ hrelu)
{
    __shared__ __align__(16) __hip_bfloat16 As[128 * 32];
    __shared__ __align__(16) __hip_bfloat16 Bs[128 * 32];
    const int tid = threadIdx.x, lane = tid & 63, wid = tid >> 6;
    const int n0 = blockIdx.x * 128, m0 = blockIdx.y * 128;
    const int p = proj[blockIdx.y >> 1];
    const __hip_bfloat16* Bp = W1T + (size_t)p * HID * EMB;
    const int wr = wid >> 1, wc = wid & 1;
    const int l4 = lane >> 4, lc = lane & 15;

    f32x4 acc[4][4] = {};
    for (int k0 = 0; k0 < EMB; k0 += 32) {
        __syncthreads();
        #pragma unroll
        for (int r = 0; r < 2; ++r) {
            int t = r * 256 + tid;
            int row = t >> 2, ko = (t & 3) * 8;
            GL16(A + (size_t)(m0 + row) * EMB + k0 + ko, &As[(r * 256 + wid * 64) * 8]);
        }
        #pragma unroll
        for (int r = 0; r < 2; ++r) {
            int t = r * 256 + tid;
            int row = t >> 2, ko = (t & 3) * 8;
            GL16(Bp + (size_t)(n0 + row) * EMB + k0 + ko, &Bs[(r * 256 + wid * 64) * 8]);
        }
        __syncthreads();
        const bf16x8* Av = (const bf16x8*)As;
        const bf16x8* Bv = (const bf16x8*)Bs;
        bf16x8 a[4], b[4];
        #pragma unroll
        for (int m = 0; m < 4; ++m) a[m] = Av[(wr * 64 + m * 16 + lc) * 4 + l4];
        #pragma unroll
        for (int n = 0; n < 4; ++n) b[n] = Bv[(wc * 64 + n * 16 + lc) * 4 + l4];
        #pragma unroll
        for (int m = 0; m < 4; ++m)
            #pragma unroll
            for (int n = 0; n < 4; ++n)
                acc[m][n] = __builtin_amdgcn_mfma_f32_16x16x32_bf16(a[m], b[n], acc[m][n], 0, 0, 0);
    }

    #pragma unroll
    for (int n = 0; n < 4; ++n) {
        int col = n0 + wc * 64 + n * 16 + lc;
        float s = sbuf[p * HID + col];
        float t = tbuf[p * HID + col];
        #pragma unroll
        for (int m = 0; m < 4; ++m)
            #pragma unroll
            for (int j = 0; j < 4; ++j) {
                int row = m0 + wr * 64 + m * 16 + l4 * 4 + j;
                float v = fmaxf(acc[m][n][j] * s + t, 0.0f);
                hrelu[(size_t)row * HID + col] = __float2bfloat16(v);
            }
    }
}

// ---------------------------------------------------------------------------
// Kernel 10: GEMM2 split-K:  out[b,n,:] += hrelu[n*256+b, kz-chunk] @ W2[p]
// grid (16, 4, 16): z = ct*4 + kz, K-chunk = 1024. out pre-zeroed; kz==0 adds b2.
// ---------------------------------------------------------------------------
__global__ __launch_bounds__(256) void gemm2(
    const __hip_bfloat16* __restrict__ Hn, const __hip_bfloat16* __restrict__ W2T,
    const int* __restrict__ proj, const float* __restrict__ b2,
    float* __restrict__ out)
{
    __shared__ __align__(16) __hip_bfloat16 As[64 * 32];
    __shared__ __align__(16) __hip_bfloat16 Bs[64 * 32];
    const int tid = threadIdx.x, lane = tid & 63, wid = tid >> 6;
    const int nmask = blockIdx.x;
    const int bc    = blockIdx.y;
    const int ct    = blockIdx.z >> 2, kz = blockIdx.z & 3;
    const int p = proj[nmask];
    const __hip_bfloat16* Ap = Hn + (size_t)(nmask * 256 + bc * 64) * HID;
    const __hip_bfloat16* Bp = W2T + ((size_t)p * OUT + ct * 64) * HID;
    const int wr = wid >> 1, wc = wid & 1;
    const int l4 = lane >> 4, lc = lane & 15;

    f32x4 acc[2][2] = {};
    for (int k0 = kz * 1024; k0 < kz * 1024 + 1024; k0 += 32) {
        __syncthreads();
        {
            int row = tid >> 2, ko = (tid & 3) * 8;
            GL16(Ap + (size_t)row * HID + k0 + ko, &As[(wid * 64) * 8]);
            GL16(Bp + (size_t)row * HID + k0 + ko, &Bs[(wid * 64) * 8]);
        }
        __syncthreads();
        const bf16x8* Av = (const bf16x8*)As;
        const bf16x8* Bv = (const bf16x8*)Bs;
        bf16x8 a[2], b[2];
        a[0] = Av[(wr * 32 +      lc) * 4 + l4];
        a[1] = Av[(wr * 32 + 16 + lc) * 4 + l4];
        b[0] = Bv[(wc * 32 +      lc) * 4 + l4];
        b[1] = Bv[(wc * 32 + 16 + lc) * 4 + l4];
        #pragma unroll
        for (int m = 0; m < 2; ++m)
            #pragma unroll
            for (int n = 0; n < 2; ++n)
                acc[m][n] = __builtin_amdgcn_mfma_f32_16x16x32_bf16(a[m], b[n], acc[m][n], 0, 0, 0);
    }

    #pragma unroll
    for (int m = 0; m < 2; ++m)
        #pragma unroll
        for (int n = 0; n < 2; ++n)
            #pragma unroll
            for (int j = 0; j < 4; ++j) {
                int bb = bc * 64 + wr * 32 + m * 16 + l4 * 4 + j;
                int oc = ct * 64 + wc * 32 + n * 16 + lc;
                float v = acc[m][n][j] + (kz == 0 ? b2[p * OUT + oc] : 0.0f);
                atomicAdd(&out[((size_t)bb * NMASK + nmask) * OUT + oc], v);
            }
}

// ---------------------------------------------------------------------------
// Kernel 11: mask_ids (int) -> float tail of output
// ---------------------------------------------------------------------------
__global__ __launch_bounds__(256) void tail_ids(const int* __restrict__ mids,
                                                float* __restrict__ out)
{
    int i = blockIdx.x * 256 + threadIdx.x;   // < 4096
    out[(size_t)MROWS * OUT + i] = (float)mids[i];
}

// ---------------------------------------------------------------------------
extern "C" void kernel_launch(void* const* d_in, const int* in_sizes, int n_in,
                              void* d_out, int out_size, void* d_ws, size_t ws_size,
                              hipStream_t stream)
{
    const float* x     = (const float*)d_in[0];
    const float* masks = (const float*)d_in[1];
    const int*   proj  = (const int*)d_in[2];
    const int*   mids  = (const int*)d_in[3];
    const float* W1    = (const float*)d_in[4];
    // d_in[5] = b1: cancels exactly under training-mode BN -> unused
    const float* gamma = (const float*)d_in[6];
    const float* beta  = (const float*)d_in[7];
    const float* W2    = (const float*)d_in[8];
    const float* b2    = (const float*)d_in[9];
    float* out = (float*)d_out;

    char* ws = (char*)d_ws;
    // layout (bytes), total 73,665,536
    __hip_bfloat16* pooledG = (__hip_bfloat16*)(ws);                   //  6,291,456
    __hip_bfloat16* W1T     = (__hip_bfloat16*)(ws + 6291456);         // 25,165,824
    __hip_bfloat16* W2T     = (__hip_bfloat16*)(ws + 31457280);        //  8,388,608
    float*          mp      = (float*)(ws + 39845888);                 //      3,072
    float*          Eh2     = (float*)(ws + 39848960);                 //     65,536
    float*          Mu      = (float*)(ws + 39914496);                 //     65,536
    float*          sbuf    = (float*)(ws + 39980032);                 //     65,536
    float*          tbuf    = (float*)(ws + 40045568);                 //     65,536
    // region R (aliased lifetimes):
    char* R = ws + 40111104;
    __hip_bfloat16* pooledT = (__hip_bfloat16*)(R);                    //  6,291,456
    float*          Cf      = (float*)(R + 6291456);                   //  2,359,296
    __hip_bfloat16* Cbf     = (__hip_bfloat16*)(R + 8650752);          //  1,179,648
    __hip_bfloat16* hrelu   = (__hip_bfloat16*)(R);                    // 33,554,432 (after Cbf consumed)

    hipMemsetAsync(Eh2, 0, 2 * NPROJ * HID * sizeof(float), stream);   // Eh2+Mu
    hipMemsetAsync(Cf, 0, EMB * EMB * sizeof(float), stream);
    hipMemsetAsync(out, 0, (size_t)MROWS * OUT * sizeof(float), stream); // for split-K atomics

    pool_mfma<<<dim3(4, BS), 256, 0, stream>>>(x, masks, pooledG);
    transpose_cvt<<<dim3(HID / 64, EMB / 64, NPROJ), 256, 0, stream>>>(W1, W1T, EMB, HID);
    transpose_cvt<<<dim3(OUT / 64, HID / 64, NPROJ), 256, 0, stream>>>(W2, W2T, HID, OUT);
    transpose_pg<<<dim3(EMB / 64, MROWS / 64), 256, 0, stream>>>(pooledG, pooledT);
    meanpool<<<EMB, 256, 0, stream>>>(pooledT, mp);
    cgemm<<<dim3(6, 6, 8), 256, 0, stream>>>(pooledT, Cf);
    cvt_c<<<(EMB * EMB) / 1024, 256, 0, stream>>>(Cf, Cbf);
    ugemm<<<dim3(6, 32, 4), 256, 0, stream>>>(W1T, Cbf, mp, Eh2, Mu);
    finalize<<<(NPROJ * HID) / 256, 256, 0, stream>>>(Eh2, Mu, gamma, beta, sbuf, tbuf);
    gemm1_sel<<<dim3(HID / 128, MROWS / 128), 256, 0, stream>>>(pooledG, W1T, proj, sbuf, tbuf, hrelu);
    gemm2<<<dim3(NMASK, BS / 64, 16), 256, 0, stream>>>(hrelu, W2T, proj, b2, out);
    tail_ids<<<(BS * NMASK) / 256, 256, 0, stream>>>(mids, out);
}

// Round 6
// 211.591 us; speedup vs baseline: 1.6138x; 1.0996x over previous
//
#include <hip/hip_runtime.h>
#include <hip/hip_bf16.h>

// Problem constants
#define BS 256
#define EMB 768
#define HW 196          // 14*14
#define NMASK 16
#define HID 4096
#define OUT 256
#define NPROJ 4
#define MROWS 4096      // BS*NMASK

typedef __attribute__((ext_vector_type(8))) short bf16x8;
typedef __attribute__((ext_vector_type(4))) float f32x4;
typedef __attribute__((ext_vector_type(8))) unsigned short u16x8;

__device__ inline float bf2f(unsigned short u) {
    unsigned int x = ((unsigned int)u) << 16;
    return __builtin_bit_cast(float, x);
}
__device__ inline short f2bfs(float f) {
    return __builtin_bit_cast(short, __float2bfloat16(f));
}

// async global->LDS, 16B per lane; lds base must be wave-uniform
#define GL16(gptr, lptr)                                                     \
    __builtin_amdgcn_global_load_lds(                                        \
        (const __attribute__((address_space(1))) void*)(gptr),               \
        (__attribute__((address_space(3))) void*)(lptr), 16, 0, 0)

// ---------------------------------------------------------------------------
// Kernel 1: masked mean pooling via MFMA.
//   pooled[b][m][e] = inv_area[m] * sum_hw masks[b][m][hw] * x[b][e][hw]
// grid (4, 256): blockIdx.x = e-chunk of 192, blockIdx.y = b. 4 waves x 48 e.
// ---------------------------------------------------------------------------
__global__ __launch_bounds__(256) void pool_mfma(
    const float* __restrict__ x, const float* __restrict__ masks,
    __hip_bfloat16* __restrict__ pooledG)
{
    __shared__ __align__(16) short afr[7 * 64 * 8];   // A-fragments, 7 KB
    __shared__ float inv[NMASK];
    const int ec = blockIdx.x, b = blockIdx.y, tid = threadIdx.x;
    const float* mb = masks + (size_t)b * NMASK * HW;

    // stage A-fragments: slot s=(kc*64+l): m=l&15, k=kc*32+(l>>4)*8 (+j)
    for (int s = tid; s < 7 * 64; s += 256) {
        int m = s & 15, kb = ((s >> 4) & 3) * 8 + (s >> 6) * 32;
        short v[8];
        #pragma unroll
        for (int j = 0; j < 8; ++j) {
            int kk = kb + j;
            v[j] = (kk < HW) ? f2bfs(mb[m * HW + kk]) : (short)0;
        }
        #pragma unroll
        for (int j = 0; j < 8; ++j) afr[s * 8 + j] = v[j];
    }
    // areas: wave 3, 4 lanes per mask
    if (tid >= 192) {
        int l = tid - 192, m = l >> 2, q = l & 3;
        float a = 0.f;
        for (int hw = q; hw < HW; hw += 4) a += mb[m * HW + hw];
        a += __shfl_xor(a, 1);
        a += __shfl_xor(a, 2);
        if (q == 0) inv[m] = 1.0f / fmaxf(a, 1.0f);
    }
    __syncthreads();

    const int lane = tid & 63, w = tid >> 6;
    const int lc = lane & 15, l4 = lane >> 4;
    const int ebase = ec * 192 + w * 48;
    const bf16x8* afv = (const bf16x8*)afr;
    f32x4 acc[3] = {};

    const float* xb0 = x + ((size_t)b * EMB + ebase + lc) * HW;

    for (int kc = 0; kc < 6; ++kc) {
        bf16x8 af = afv[kc * 64 + lane];
        float4 u[3][2];
        #pragma unroll
        for (int t = 0; t < 3; ++t) {
            const float* xr = xb0 + (size_t)(t * 16) * HW + kc * 32 + l4 * 8;
            u[t][0] = *(const float4*)(xr);
            u[t][1] = *(const float4*)(xr + 4);
        }
        #pragma unroll
        for (int t = 0; t < 3; ++t) {
            bf16x8 bf;
            bf[0] = f2bfs(u[t][0].x); bf[1] = f2bfs(u[t][0].y);
            bf[2] = f2bfs(u[t][0].z); bf[3] = f2bfs(u[t][0].w);
            bf[4] = f2bfs(u[t][1].x); bf[5] = f2bfs(u[t][1].y);
            bf[6] = f2bfs(u[t][1].z); bf[7] = f2bfs(u[t][1].w);
            acc[t] = __builtin_amdgcn_mfma_f32_16x16x32_bf16(af, bf, acc[t], 0, 0, 0);
        }
    }
    {   // tail K-chunk: k=192..196 valid (l4==0 only), rest zero (A also zero)
        bf16x8 af = afv[6 * 64 + lane];
        #pragma unroll
        for (int t = 0; t < 3; ++t) {
            bf16x8 bf = {};
            if (l4 == 0) {
                float4 u0 = *(const float4*)(xb0 + (size_t)(t * 16) * HW + 192);
                bf[0] = f2bfs(u0.x); bf[1] = f2bfs(u0.y);
                bf[2] = f2bfs(u0.z); bf[3] = f2bfs(u0.w);
            }
            acc[t] = __builtin_amdgcn_mfma_f32_16x16x32_bf16(af, bf, acc[t], 0, 0, 0);
        }
    }

    // epilogue: D col(lane&15)=e, row((lane>>4)*4+j)=m ; scale by inv[m]
    #pragma unroll
    for (int t = 0; t < 3; ++t) {
        int e = ebase + t * 16 + lc;
        #pragma unroll
        for (int j = 0; j < 4; ++j) {
            int m = l4 * 4 + j;
            pooledG[((size_t)m * 256 + b) * EMB + e] =
                __float2bfloat16(acc[t][j] * inv[m]);
        }
    }
}

// ---------------------------------------------------------------------------
// Kernel 2: transpose + f32->bf16.  src [gz][R][C] f32 -> dst [gz][C][R] bf16
// ---------------------------------------------------------------------------
__global__ __launch_bounds__(256) void transpose_cvt(
    const float* __restrict__ src, __hip_bfloat16* __restrict__ dst, int R, int C)
{
    __shared__ float tile[64][65];
    const float* s = src + (size_t)blockIdx.z * R * C;
    __hip_bfloat16* d = dst + (size_t)blockIdx.z * R * C;
    const int c0 = blockIdx.x * 64, r0 = blockIdx.y * 64, tid = threadIdx.x;
    for (int i = tid; i < 4096; i += 256) {
        int r = i >> 6, c = i & 63;
        tile[r][c] = s[(size_t)(r0 + r) * C + c0 + c];
    }
    __syncthreads();
    for (int i = tid; i < 4096; i += 256) {
        int c = i >> 6, r = i & 63;
        d[(size_t)(c0 + c) * R + r0 + r] = __float2bfloat16(tile[r][c]);
    }
}

// ---------------------------------------------------------------------------
// Kernel 3: bf16 transpose pooledG [4096][768] -> pooledT [768][4096]
// ---------------------------------------------------------------------------
__global__ __launch_bounds__(256) void transpose_pg(
    const __hip_bfloat16* __restrict__ src, __hip_bfloat16* __restrict__ dst)
{
    __shared__ __hip_bfloat16 tile[64][65];
    const int c0 = blockIdx.x * 64, r0 = blockIdx.y * 64, tid = threadIdx.x;
    for (int i = tid; i < 4096; i += 256) {
        int r = i >> 6, c = i & 63;
        tile[r][c] = src[(size_t)(r0 + r) * EMB + c0 + c];
    }
    __syncthreads();
    for (int i = tid; i < 4096; i += 256) {
        int c = i >> 6, r = i & 63;
        dst[(size_t)(c0 + c) * MROWS + r0 + r] = tile[r][c];
    }
}

// ---------------------------------------------------------------------------
// Kernel 4: mp[e] = (1/4096) sum_r pooledT[e][r]
// ---------------------------------------------------------------------------
__global__ __launch_bounds__(256) void meanpool(
    const __hip_bfloat16* __restrict__ PT, float* __restrict__ mp)
{
    const int e = blockIdx.x, tid = threadIdx.x;
    const u16x8* p = (const u16x8*)(PT + (size_t)e * MROWS);
    u16x8 v1 = p[tid], v2 = p[tid + 256];
    float s = 0.f;
    #pragma unroll
    for (int j = 0; j < 8; ++j) s += bf2f((unsigned short)v1[j]) + bf2f((unsigned short)v2[j]);
    #pragma unroll
    for (int o = 1; o < 64; o <<= 1) s += __shfl_xor(s, o);
    __shared__ float wsum[4];
    if ((tid & 63) == 0) wsum[tid >> 6] = s;
    __syncthreads();
    if (tid == 0) mp[e] = (wsum[0] + wsum[1] + wsum[2] + wsum[3]) * (1.0f / 4096.0f);
}

// ---------------------------------------------------------------------------
// Kernel 5: C GEMM (split-K, partial stores): Cpart[kz][i][j] = partial sums
// grid (6, 6, 8)  K-chunk = 512.  No atomics, no pre-zero.
// ---------------------------------------------------------------------------
__global__ __launch_bounds__(256) void cgemm(
    const __hip_bfloat16* __restrict__ PT, float* __restrict__ Cpart)
{
    __shared__ __align__(16) __hip_bfloat16 As[128 * 32];
    __shared__ __align__(16) __hip_bfloat16 Bs[128 * 32];
    const int tid = threadIdx.x, lane = tid & 63, wid = tid >> 6;
    const int n0 = blockIdx.x * 128, m0 = blockIdx.y * 128, kbase = blockIdx.z * 512;
    float* Cp = Cpart + (size_t)blockIdx.z * EMB * EMB;
    const int wr = wid >> 1, wc = wid & 1;
    const int l4 = lane >> 4, lc = lane & 15;

    f32x4 acc[4][4] = {};
    for (int k0 = kbase; k0 < kbase + 512; k0 += 32) {
        __syncthreads();
        #pragma unroll
        for (int r = 0; r < 2; ++r) {
            int t = r * 256 + tid;
            int row = t >> 2, ko = (t & 3) * 8;
            GL16(PT + (size_t)(m0 + row) * MROWS + k0 + ko, &As[(r * 256 + wid * 64) * 8]);
        }
        #pragma unroll
        for (int r = 0; r < 2; ++r) {
            int t = r * 256 + tid;
            int row = t >> 2, ko = (t & 3) * 8;
            GL16(PT + (size_t)(n0 + row) * MROWS + k0 + ko, &Bs[(r * 256 + wid * 64) * 8]);
        }
        __syncthreads();
        const bf16x8* Av = (const bf16x8*)As;
        const bf16x8* Bv = (const bf16x8*)Bs;
        bf16x8 a[4], b[4];
        #pragma unroll
        for (int m = 0; m < 4; ++m) a[m] = Av[(wr * 64 + m * 16 + lc) * 4 + l4];
        #pragma unroll
        for (int n = 0; n < 4; ++n) b[n] = Bv[(wc * 64 + n * 16 + lc) * 4 + l4];
        #pragma unroll
        for (int m = 0; m < 4; ++m)
            #pragma unroll
            for (int n = 0; n < 4; ++n)
                acc[m][n] = __builtin_amdgcn_mfma_f32_16x16x32_bf16(a[m], b[n], acc[m][n], 0, 0, 0);
    }
    #pragma unroll
    for (int m = 0; m < 4; ++m)
        #pragma unroll
        for (int n = 0; n < 4; ++n)
            #pragma unroll
            for (int j = 0; j < 4; ++j) {
                int row = m0 + wr * 64 + m * 16 + l4 * 4 + j;
                int col = n0 + wc * 64 + n * 16 + lc;
                Cp[(size_t)row * EMB + col] = acc[m][n][j];
            }
}

// ---------------------------------------------------------------------------
// Kernel 6: reduce 8 Cpart slices -> Cbf bf16 with 1/N fold
// ---------------------------------------------------------------------------
__global__ __launch_bounds__(256) void cvt_c(
    const float* __restrict__ Cpart, __hip_bfloat16* __restrict__ Cbf)
{
    int i = (blockIdx.x * 256 + threadIdx.x) * 4;   // < 768*768
    float sx = 0.f, sy = 0.f, sz = 0.f, sw = 0.f;
    #pragma unroll
    for (int kz = 0; kz < 8; ++kz) {
        float4 v = *(const float4*)(Cpart + (size_t)kz * EMB * EMB + i);
        sx += v.x; sy += v.y; sz += v.z; sw += v.w;
    }
    const float s = 1.0f / 4096.0f;
    Cbf[i + 0] = __float2bfloat16(sx * s);
    Cbf[i + 1] = __float2bfloat16(sy * s);
    Cbf[i + 2] = __float2bfloat16(sz * s);
    Cbf[i + 3] = __float2bfloat16(sw * s);
}

// ---------------------------------------------------------------------------
// Kernel 7: U GEMM + fused stats (partial stores).  NOTE: the row-dot is a
// partial over this wave's 64 cols, and waves wc=0/wc=1 share the same row —
// so partials are indexed by (bx*2 + wc) to avoid the overwrite bug (R5).
// grid (6, 32, 4) -> 12 partial slices.
// ---------------------------------------------------------------------------
__global__ __launch_bounds__(256) void ugemm(
    const __hip_bfloat16* __restrict__ W1T, const __hip_bfloat16* __restrict__ Cbf,
    const float* __restrict__ mp,
    float* __restrict__ Eh2p, float* __restrict__ Mup)
{
    __shared__ __align__(16) __hip_bfloat16 As[128 * 32];
    __shared__ __align__(16) __hip_bfloat16 Bs[128 * 32];
    const int tid = threadIdx.x, lane = tid & 63, wid = tid >> 6;
    const int n0 = blockIdx.x * 128, m0 = blockIdx.y * 128, p = blockIdx.z;
    const __hip_bfloat16* Ap = W1T + (size_t)p * HID * EMB;
    const int wr = wid >> 1, wc = wid & 1;
    const int l4 = lane >> 4, lc = lane & 15;

    f32x4 acc[4][4] = {};
    for (int k0 = 0; k0 < EMB; k0 += 32) {
        __syncthreads();
        #pragma unroll
        for (int r = 0; r < 2; ++r) {
            int t = r * 256 + tid;
            int row = t >> 2, ko = (t & 3) * 8;
            GL16(Ap + (size_t)(m0 + row) * EMB + k0 + ko, &As[(r * 256 + wid * 64) * 8]);
        }
        #pragma unroll
        for (int r = 0; r < 2; ++r) {
            int t = r * 256 + tid;
            int row = t >> 2, ko = (t & 3) * 8;
            GL16(Cbf + (size_t)(n0 + row) * EMB + k0 + ko, &Bs[(r * 256 + wid * 64) * 8]);
        }
        __syncthreads();
        const bf16x8* Av = (const bf16x8*)As;
        const bf16x8* Bv = (const bf16x8*)Bs;
        bf16x8 a[4], b[4];
        #pragma unroll
        for (int m = 0; m < 4; ++m) a[m] = Av[(wr * 64 + m * 16 + lc) * 4 + l4];
        #pragma unroll
        for (int n = 0; n < 4; ++n) b[n] = Bv[(wc * 64 + n * 16 + lc) * 4 + l4];
        #pragma unroll
        for (int m = 0; m < 4; ++m)
            #pragma unroll
            for (int n = 0; n < 4; ++n)
                acc[m][n] = __builtin_amdgcn_mfma_f32_16x16x32_bf16(a[m], b[n], acc[m][n], 0, 0, 0);
    }

    float mpv[4];
    #pragma unroll
    for (int n = 0; n < 4; ++n) mpv[n] = mp[n0 + wc * 64 + n * 16 + lc];
    #pragma unroll
    for (int m = 0; m < 4; ++m) {
        #pragma unroll
        for (int j = 0; j < 4; ++j) {
            int row = m0 + wr * 64 + m * 16 + l4 * 4 + j;
            const __hip_bfloat16* wrow = Ap + (size_t)row * EMB;
            float e2 = 0.f, mu = 0.f;
            #pragma unroll
            for (int n = 0; n < 4; ++n) {
                int col = n0 + wc * 64 + n * 16 + lc;
                float wv = bf2f(__builtin_bit_cast(unsigned short, wrow[col]));
                e2 += acc[m][n][j] * wv;
                mu += mpv[n] * wv;
            }
            e2 += __shfl_xor(e2, 1); e2 += __shfl_xor(e2, 2);
            e2 += __shfl_xor(e2, 4); e2 += __shfl_xor(e2, 8);
            mu += __shfl_xor(mu, 1); mu += __shfl_xor(mu, 2);
            mu += __shfl_xor(mu, 4); mu += __shfl_xor(mu, 8);
            if (lc == 0) {
                size_t idx = (((size_t)blockIdx.x * 2 + wc) * NPROJ + p) * HID + row;
                Eh2p[idx] = e2;
                Mup [idx] = mu;
            }
        }
    }
}

// ---------------------------------------------------------------------------
// Kernel 8: finalize (reduce 12 partials): s = gamma*rsqrt(var+eps), t = beta-mu*s
// ---------------------------------------------------------------------------
__global__ __launch_bounds__(256) void finalize(
    const float* __restrict__ Eh2p, const float* __restrict__ Mup,
    const float* __restrict__ gamma, const float* __restrict__ beta,
    float* __restrict__ sbuf, float* __restrict__ tbuf)
{
    int i = blockIdx.x * 256 + threadIdx.x;            // < 16384
    float e2 = 0.f, mu = 0.f;
    #pragma unroll
    for (int bx = 0; bx < 12; ++bx) {
        e2 += Eh2p[bx * (NPROJ * HID) + i];
        mu += Mup [bx * (NPROJ * HID) + i];
    }
    float var = e2 - mu * mu;
    float is  = rsqrtf(fmaxf(var, 0.0f) + 1e-5f);
    float sc  = gamma[i] * is;
    sbuf[i] = sc;
    tbuf[i] = beta[i] - mu * sc;
}

// ---------------------------------------------------------------------------
// Kernel 9: selected GEMM1 + fused BN+ReLU
// grid (HID/128=32, MROWS/128=32)
// ---------------------------------------------------------------------------
__global__ __launch_bounds__(256) void gemm1_sel(
    const __hip_bfloat16* __restrict__ A, const __hip_bfloat16* __restrict__ W1T,
    const int* __restrict__ proj,
    const float* __restrict__ sbuf, const float* __restrict__ tbuf,
    __hip_bfloat16* __restrict__ hrelu)
{
    __shared__ __align__(16) __hip_bfloat16 As[128 * 32];
    __shared__ __align__(16) __hip_bfloat16 Bs[128 * 32];
    const int tid = threadIdx.x, lane = tid & 63, wid = tid >> 6;
    const int n0 = blockIdx.x * 128, m0 = blockIdx.y * 128;
    const int p = proj[blockIdx.y >> 1];
    const __hip_bfloat16* Bp = W1T + (size_t)p * HID * EMB;
    const int wr = wid >> 1, wc = wid & 1;
    const int l4 = lane >> 4, lc = lane & 15;

    f32x4 acc[4][4] = {};
    for (int k0 = 0; k0 < EMB; k0 += 32) {
        __syncthreads();
        #pragma unroll
        for (int r = 0; r < 2; ++r) {
            int t = r * 256 + tid;
            int row = t >> 2, ko = (t & 3) * 8;
            GL16(A + (size_t)(m0 + row) * EMB + k0 + ko, &As[(r * 256 + wid * 64) * 8]);
        }
        #pragma unroll
        for (int r = 0; r < 2; ++r) {
            int t = r * 256 + tid;
            int row = t >> 2, ko = (t & 3) * 8;
            GL16(Bp + (size_t)(n0 + row) * EMB + k0 + ko, &Bs[(r * 256 + wid * 64) * 8]);
        }
        __syncthreads();
        const bf16x8* Av = (const bf16x8*)As;
        const bf16x8* Bv = (const bf16x8*)Bs;
        bf16x8 a[4], b[4];
        #pragma unroll
        for (int m = 0; m < 4; ++m) a[m] = Av[(wr * 64 + m * 16 + lc) * 4 + l4];
        #pragma unroll
        for (int n = 0; n < 4; ++n) b[n] = Bv[(wc * 64 + n * 16 + lc) * 4 + l4];
        #pragma unroll
        for (int m = 0; m < 4; ++m)
            #pragma unroll
            for (int n = 0; n < 4; ++n)
                acc[m][n] = __builtin_amdgcn_mfma_f32_16x16x32_bf16(a[m], b[n], acc[m][n], 0, 0, 0);
    }

    #pragma unroll
    for (int n = 0; n < 4; ++n) {
        int col = n0 + wc * 64 + n * 16 + lc;
        float s = sbuf[p * HID + col];
        float t = tbuf[p * HID + col];
        #pragma unroll
        for (int m = 0; m < 4; ++m)
            #pragma unroll
            for (int j = 0; j < 4; ++j) {
                int row = m0 + wr * 64 + m * 16 + l4 * 4 + j;
                float v = fmaxf(acc[m][n][j] * s + t, 0.0f);
                hrelu[(size_t)row * HID + col] = __float2bfloat16(v);
            }
    }
}

// ---------------------------------------------------------------------------
// Kernel 10: GEMM2 split-K (partial stores): Opart[kz] = chunk result
// grid (16, 4, 16): z = ct*4 + kz, K-chunk = 1024.
// ---------------------------------------------------------------------------
__global__ __launch_bounds__(256) void gemm2(
    const __hip_bfloat16* __restrict__ Hn, const __hip_bfloat16* __restrict__ W2T,
    const int* __restrict__ proj, float* __restrict__ Opart)
{
    __shared__ __align__(16) __hip_bfloat16 As[64 * 32];
    __shared__ __align__(16) __hip_bfloat16 Bs[64 * 32];
    const int tid = threadIdx.x, lane = tid & 63, wid = tid >> 6;
    const int nmask = blockIdx.x;
    const int bc    = blockIdx.y;
    const int ct    = blockIdx.z >> 2, kz = blockIdx.z & 3;
    const int p = proj[nmask];
    const __hip_bfloat16* Ap = Hn + (size_t)(nmask * 256 + bc * 64) * HID;
    const __hip_bfloat16* Bp = W2T + ((size_t)p * OUT + ct * 64) * HID;
    float* Op = Opart + (size_t)kz * MROWS * OUT;
    const int wr = wid >> 1, wc = wid & 1;
    const int l4 = lane >> 4, lc = lane & 15;

    f32x4 acc[2][2] = {};
    for (int k0 = kz * 1024; k0 < kz * 1024 + 1024; k0 += 32) {
        __syncthreads();
        {
            int row = tid >> 2, ko = (tid & 3) * 8;
            GL16(Ap + (size_t)row * HID + k0 + ko, &As[(wid * 64) * 8]);
            GL16(Bp + (size_t)row * HID + k0 + ko, &Bs[(wid * 64) * 8]);
        }
        __syncthreads();
        const bf16x8* Av = (const bf16x8*)As;
        const bf16x8* Bv = (const bf16x8*)Bs;
        bf16x8 a[2], b[2];
        a[0] = Av[(wr * 32 +      lc) * 4 + l4];
        a[1] = Av[(wr * 32 + 16 + lc) * 4 + l4];
        b[0] = Bv[(wc * 32 +      lc) * 4 + l4];
        b[1] = Bv[(wc * 32 + 16 + lc) * 4 + l4];
        #pragma unroll
        for (int m = 0; m < 2; ++m)
            #pragma unroll
            for (int n = 0; n < 2; ++n)
                acc[m][n] = __builtin_amdgcn_mfma_f32_16x16x32_bf16(a[m], b[n], acc[m][n], 0, 0, 0);
    }

    #pragma unroll
    for (int m = 0; m < 2; ++m)
        #pragma unroll
        for (int n = 0; n < 2; ++n)
            #pragma unroll
            for (int j = 0; j < 4; ++j) {
                int bb = bc * 64 + wr * 32 + m * 16 + l4 * 4 + j;
                int oc = ct * 64 + wc * 32 + n * 16 + lc;
                Op[((size_t)bb * NMASK + nmask) * OUT + oc] = acc[m][n][j];
            }
}

// ---------------------------------------------------------------------------
// Kernel 11: reduce 4 Opart slices + b2 -> out ; fused mask_ids tail
// grid 1024
// ---------------------------------------------------------------------------
__global__ __launch_bounds__(256) void reduce_out(
    const float* __restrict__ Opart, const float* __restrict__ b2,
    const int* __restrict__ proj, const int* __restrict__ mids,
    float* __restrict__ out)
{
    int i = (blockIdx.x * 256 + threadIdx.x) * 4;   // < 4096*256
    float sx = 0.f, sy = 0.f, sz = 0.f, sw = 0.f;
    #pragma unroll
    for (int kz = 0; kz < 4; ++kz) {
        float4 v = *(const float4*)(Opart + (size_t)kz * MROWS * OUT + i);
        sx += v.x; sy += v.y; sz += v.z; sw += v.w;
    }
    int nm = (i >> 8) & 15;
    int p  = proj[nm];
    float4 bv = *(const float4*)(b2 + p * OUT + (i & 255));
    float4 r;
    r.x = sx + bv.x; r.y = sy + bv.y; r.z = sz + bv.z; r.w = sw + bv.w;
    *(float4*)(out + i) = r;
    if (blockIdx.x < 16) {
        int t = blockIdx.x * 256 + threadIdx.x;     // < 4096
        out[(size_t)MROWS * OUT + t] = (float)mids[t];
    }
}

// ---------------------------------------------------------------------------
extern "C" void kernel_launch(void* const* d_in, const int* in_sizes, int n_in,
                              void* d_out, int out_size, void* d_ws, size_t ws_size,
                              hipStream_t stream)
{
    const float* x     = (const float*)d_in[0];
    const float* masks = (const float*)d_in[1];
    const int*   proj  = (const int*)d_in[2];
    const int*   mids  = (const int*)d_in[3];
    const float* W1    = (const float*)d_in[4];
    // d_in[5] = b1: cancels exactly under training-mode BN -> unused
    const float* gamma = (const float*)d_in[6];
    const float* beta  = (const float*)d_in[7];
    const float* W2    = (const float*)d_in[8];
    const float* b2    = (const float*)d_in[9];
    float* out = (float*)d_out;

    char* ws = (char*)d_ws;
    // layout (bytes), total ~92 MB
    __hip_bfloat16* pooledG = (__hip_bfloat16*)(ws);                   //  6,291,456
    __hip_bfloat16* W1T     = (__hip_bfloat16*)(ws + 6291456);         // 25,165,824
    __hip_bfloat16* W2T     = (__hip_bfloat16*)(ws + 31457280);        //  8,388,608
    float*          mp      = (float*)(ws + 39845888);                 //      3,072
    float*          Eh2p    = (float*)(ws + 39848960);                 //    786,432 (12 slices)
    float*          Mup     = (float*)(ws + 40635392);                 //    786,432 (12 slices)
    float*          sbuf    = (float*)(ws + 41421824);                 //     65,536
    float*          tbuf    = (float*)(ws + 41487360);                 //     65,536
    // region R (aliased lifetimes):
    char* R = ws + 41552896;
    __hip_bfloat16* pooledT = (__hip_bfloat16*)(R);                    //  6,291,456
    float*          Cpart   = (float*)(R + 6291456);                   // 18,874,368
    __hip_bfloat16* Cbf     = (__hip_bfloat16*)(R + 25165824);         //  1,179,648
    __hip_bfloat16* hrelu   = (__hip_bfloat16*)(R);                    // 33,554,432 (after pooledT/Cpart/Cbf consumed)
    float*          Opart   = (float*)(R + 33554432);                  // 16,777,216

    pool_mfma<<<dim3(4, BS), 256, 0, stream>>>(x, masks, pooledG);
    transpose_cvt<<<dim3(HID / 64, EMB / 64, NPROJ), 256, 0, stream>>>(W1, W1T, EMB, HID);
    transpose_cvt<<<dim3(OUT / 64, HID / 64, NPROJ), 256, 0, stream>>>(W2, W2T, HID, OUT);
    transpose_pg<<<dim3(EMB / 64, MROWS / 64), 256, 0, stream>>>(pooledG, pooledT);
    meanpool<<<EMB, 256, 0, stream>>>(pooledT, mp);
    cgemm<<<dim3(6, 6, 8), 256, 0, stream>>>(pooledT, Cpart);
    cvt_c<<<(EMB * EMB) / 1024, 256, 0, stream>>>(Cpart, Cbf);
    ugemm<<<dim3(6, 32, 4), 256, 0, stream>>>(W1T, Cbf, mp, Eh2p, Mup);
    finalize<<<(NPROJ * HID) / 256, 256, 0, stream>>>(Eh2p, Mup, gamma, beta, sbuf, tbuf);
    gemm1_sel<<<dim3(HID / 128, MROWS / 128), 256, 0, stream>>>(pooledG, W1T, proj, sbuf, tbuf, hrelu);
    gemm2<<<dim3(NMASK, BS / 64, 16), 256, 0, stream>>>(hrelu, W2T, proj, Opart);
    reduce_out<<<(MROWS * OUT) / 1024, 256, 0, stream>>>(Opart, b2, proj, mids, out);
}

// Round 8
// 204.826 us; speedup vs baseline: 1.6671x; 1.0330x over previous
//
#include <hip/hip_runtime.h>
#include <hip/hip_bf16.h>

// Problem constants
#define BS 256
#define EMB 768
#define HW 196          // 14*14
#define NMASK 16
#define HID 4096
#define OUT 256
#define NPROJ 4
#define MROWS 4096      // BS*NMASK

typedef __attribute__((ext_vector_type(8))) short bf16x8;
typedef __attribute__((ext_vector_type(4))) float f32x4;
typedef __attribute__((ext_vector_type(8))) unsigned short u16x8;

__device__ inline float bf2f(unsigned short u) {
    unsigned int x = ((unsigned int)u) << 16;
    return __builtin_bit_cast(float, x);
}
__device__ inline short f2bfs(float f) {
    return __builtin_bit_cast(short, __float2bfloat16(f));
}

// async global->LDS, 16B per lane; lds base must be wave-uniform
#define GL16(gptr, lptr)                                                     \
    __builtin_amdgcn_global_load_lds(                                        \
        (const __attribute__((address_space(1))) void*)(gptr),               \
        (__attribute__((address_space(3))) void*)(lptr), 16, 0, 0)

// ---------------------------------------------------------------------------
// Kernel 1: masked mean pooling via MFMA.
// grid (4, 256): blockIdx.x = e-chunk of 192, blockIdx.y = b. 4 waves x 48 e.
// ---------------------------------------------------------------------------
__global__ __launch_bounds__(256) void pool_mfma(
    const float* __restrict__ x, const float* __restrict__ masks,
    __hip_bfloat16* __restrict__ pooledG)
{
    __shared__ __align__(16) short afr[7 * 64 * 8];   // A-fragments, 7 KB
    __shared__ float inv[NMASK];
    const int ec = blockIdx.x, b = blockIdx.y, tid = threadIdx.x;
    const float* mb = masks + (size_t)b * NMASK * HW;

    for (int s = tid; s < 7 * 64; s += 256) {
        int m = s & 15, kb = ((s >> 4) & 3) * 8 + (s >> 6) * 32;
        short v[8];
        #pragma unroll
        for (int j = 0; j < 8; ++j) {
            int kk = kb + j;
            v[j] = (kk < HW) ? f2bfs(mb[m * HW + kk]) : (short)0;
        }
        #pragma unroll
        for (int j = 0; j < 8; ++j) afr[s * 8 + j] = v[j];
    }
    if (tid >= 192) {
        int l = tid - 192, m = l >> 2, q = l & 3;
        float a = 0.f;
        for (int hw = q; hw < HW; hw += 4) a += mb[m * HW + hw];
        a += __shfl_xor(a, 1);
        a += __shfl_xor(a, 2);
        if (q == 0) inv[m] = 1.0f / fmaxf(a, 1.0f);
    }
    __syncthreads();

    const int lane = tid & 63, w = tid >> 6;
    const int lc = lane & 15, l4 = lane >> 4;
    const int ebase = ec * 192 + w * 48;
    const bf16x8* afv = (const bf16x8*)afr;
    f32x4 acc[3] = {};

    const float* xb0 = x + ((size_t)b * EMB + ebase + lc) * HW;

    for (int kc = 0; kc < 6; ++kc) {
        bf16x8 af = afv[kc * 64 + lane];
        float4 u[3][2];
        #pragma unroll
        for (int t = 0; t < 3; ++t) {
            const float* xr = xb0 + (size_t)(t * 16) * HW + kc * 32 + l4 * 8;
            u[t][0] = *(const float4*)(xr);
            u[t][1] = *(const float4*)(xr + 4);
        }
        #pragma unroll
        for (int t = 0; t < 3; ++t) {
            bf16x8 bf;
            bf[0] = f2bfs(u[t][0].x); bf[1] = f2bfs(u[t][0].y);
            bf[2] = f2bfs(u[t][0].z); bf[3] = f2bfs(u[t][0].w);
            bf[4] = f2bfs(u[t][1].x); bf[5] = f2bfs(u[t][1].y);
            bf[6] = f2bfs(u[t][1].z); bf[7] = f2bfs(u[t][1].w);
            acc[t] = __builtin_amdgcn_mfma_f32_16x16x32_bf16(af, bf, acc[t], 0, 0, 0);
        }
    }
    {   // tail K-chunk
        bf16x8 af = afv[6 * 64 + lane];
        #pragma unroll
        for (int t = 0; t < 3; ++t) {
            bf16x8 bf = {};
            if (l4 == 0) {
                float4 u0 = *(const float4*)(xb0 + (size_t)(t * 16) * HW + 192);
                bf[0] = f2bfs(u0.x); bf[1] = f2bfs(u0.y);
                bf[2] = f2bfs(u0.z); bf[3] = f2bfs(u0.w);
            }
            acc[t] = __builtin_amdgcn_mfma_f32_16x16x32_bf16(af, bf, acc[t], 0, 0, 0);
        }
    }

    #pragma unroll
    for (int t = 0; t < 3; ++t) {
        int e = ebase + t * 16 + lc;
        #pragma unroll
        for (int j = 0; j < 4; ++j) {
            int m = l4 * 4 + j;
            pooledG[((size_t)m * 256 + b) * EMB + e] =
                __float2bfloat16(acc[t][j] * inv[m]);
        }
    }
}

// ---------------------------------------------------------------------------
// Kernel 2: transpose + f32->bf16.  src [gz][R][C] f32 -> dst [gz][C][R] bf16
// ---------------------------------------------------------------------------
__global__ __launch_bounds__(256) void transpose_cvt(
    const float* __restrict__ src, __hip_bfloat16* __restrict__ dst, int R, int C)
{
    __shared__ float tile[64][65];
    const float* s = src + (size_t)blockIdx.z * R * C;
    __hip_bfloat16* d = dst + (size_t)blockIdx.z * R * C;
    const int c0 = blockIdx.x * 64, r0 = blockIdx.y * 64, tid = threadIdx.x;
    for (int i = tid; i < 4096; i += 256) {
        int r = i >> 6, c = i & 63;
        tile[r][c] = s[(size_t)(r0 + r) * C + c0 + c];
    }
    __syncthreads();
    for (int i = tid; i < 4096; i += 256) {
        int c = i >> 6, r = i & 63;
        d[(size_t)(c0 + c) * R + r0 + r] = __float2bfloat16(tile[r][c]);
    }
}

// ---------------------------------------------------------------------------
// Kernel 3: bf16 transpose pooledG [4096][768] -> pooledT [768][4096]
// ---------------------------------------------------------------------------
__global__ __launch_bounds__(256) void transpose_pg(
    const __hip_bfloat16* __restrict__ src, __hip_bfloat16* __restrict__ dst)
{
    __shared__ __hip_bfloat16 tile[64][65];
    const int c0 = blockIdx.x * 64, r0 = blockIdx.y * 64, tid = threadIdx.x;
    for (int i = tid; i < 4096; i += 256) {
        int r = i >> 6, c = i & 63;
        tile[r][c] = src[(size_t)(r0 + r) * EMB + c0 + c];
    }
    __syncthreads();
    for (int i = tid; i < 4096; i += 256) {
        int c = i >> 6, r = i & 63;
        dst[(size_t)(c0 + c) * MROWS + r0 + r] = tile[r][c];
    }
}

// ---------------------------------------------------------------------------
// Kernel 4: mp[e] = (1/4096) sum_r pooledT[e][r]
// ---------------------------------------------------------------------------
__global__ __launch_bounds__(256) void meanpool(
    const __hip_bfloat16* __restrict__ PT, float* __restrict__ mp)
{
    const int e = blockIdx.x, tid = threadIdx.x;
    const u16x8* p = (const u16x8*)(PT + (size_t)e * MROWS);
    u16x8 v1 = p[tid], v2 = p[tid + 256];
    float s = 0.f;
    #pragma unroll
    for (int j = 0; j < 8; ++j) s += bf2f((unsigned short)v1[j]) + bf2f((unsigned short)v2[j]);
    #pragma unroll
    for (int o = 1; o < 64; o <<= 1) s += __shfl_xor(s, o);
    __shared__ float wsum[4];
    if ((tid & 63) == 0) wsum[tid >> 6] = s;
    __syncthreads();
    if (tid == 0) mp[e] = (wsum[0] + wsum[1] + wsum[2] + wsum[3]) * (1.0f / 4096.0f);
}

// ---------------------------------------------------------------------------
// Kernel 5: C GEMM (split-K, partial stores): Cpart[kz][i][j]
// grid (6, 6, 8)  K-chunk = 512.
// ---------------------------------------------------------------------------
__global__ __launch_bounds__(256) void cgemm(
    const __hip_bfloat16* __restrict__ PT, float* __restrict__ Cpart)
{
    __shared__ __align__(16) __hip_bfloat16 As[128 * 32];
    __shared__ __align__(16) __hip_bfloat16 Bs[128 * 32];
    const int tid = threadIdx.x, lane = tid & 63, wid = tid >> 6;
    const int n0 = blockIdx.x * 128, m0 = blockIdx.y * 128, kbase = blockIdx.z * 512;
    float* Cp = Cpart + (size_t)blockIdx.z * EMB * EMB;
    const int wr = wid >> 1, wc = wid & 1;
    const int l4 = lane >> 4, lc = lane & 15;

    f32x4 acc[4][4] = {};
    for (int k0 = kbase; k0 < kbase + 512; k0 += 32) {
        __syncthreads();
        #pragma unroll
        for (int r = 0; r < 2; ++r) {
            int t = r * 256 + tid;
            int row = t >> 2, ko = (t & 3) * 8;
            GL16(PT + (size_t)(m0 + row) * MROWS + k0 + ko, &As[(r * 256 + wid * 64) * 8]);
        }
        #pragma unroll
        for (int r = 0; r < 2; ++r) {
            int t = r * 256 + tid;
            int row = t >> 2, ko = (t & 3) * 8;
            GL16(PT + (size_t)(n0 + row) * MROWS + k0 + ko, &Bs[(r * 256 + wid * 64) * 8]);
        }
        __syncthreads();
        const bf16x8* Av = (const bf16x8*)As;
        const bf16x8* Bv = (const bf16x8*)Bs;
        bf16x8 a[4], b[4];
        #pragma unroll
        for (int m = 0; m < 4; ++m) a[m] = Av[(wr * 64 + m * 16 + lc) * 4 + l4];
        #pragma unroll
        for (int n = 0; n < 4; ++n) b[n] = Bv[(wc * 64 + n * 16 + lc) * 4 + l4];
        #pragma unroll
        for (int m = 0; m < 4; ++m)
            #pragma unroll
            for (int n = 0; n < 4; ++n)
                acc[m][n] = __builtin_amdgcn_mfma_f32_16x16x32_bf16(a[m], b[n], acc[m][n], 0, 0, 0);
    }
    #pragma unroll
    for (int m = 0; m < 4; ++m)
        #pragma unroll
        for (int n = 0; n < 4; ++n)
            #pragma unroll
            for (int j = 0; j < 4; ++j) {
                int row = m0 + wr * 64 + m * 16 + l4 * 4 + j;
                int col = n0 + wc * 64 + n * 16 + lc;
                Cp[(size_t)row * EMB + col] = acc[m][n][j];
            }
}

// ---------------------------------------------------------------------------
// Kernel 6: reduce 8 Cpart slices -> Cbf bf16 with 1/N fold
// ---------------------------------------------------------------------------
__global__ __launch_bounds__(256) void cvt_c(
    const float* __restrict__ Cpart, __hip_bfloat16* __restrict__ Cbf)
{
    int i = (blockIdx.x * 256 + threadIdx.x) * 4;   // < 768*768
    float sx = 0.f, sy = 0.f, sz = 0.f, sw = 0.f;
    #pragma unroll
    for (int kz = 0; kz < 8; ++kz) {
        float4 v = *(const float4*)(Cpart + (size_t)kz * EMB * EMB + i);
        sx += v.x; sy += v.y; sz += v.z; sw += v.w;
    }
    const float s = 1.0f / 4096.0f;
    Cbf[i + 0] = __float2bfloat16(sx * s);
    Cbf[i + 1] = __float2bfloat16(sy * s);
    Cbf[i + 2] = __float2bfloat16(sz * s);
    Cbf[i + 3] = __float2bfloat16(sw * s);
}

// ---------------------------------------------------------------------------
// Kernel 7: U GEMM + fused stats (partial stores indexed by (bx*2+wc)).
// grid (6, 32, 4) -> 12 partial slices.
// ---------------------------------------------------------------------------
__global__ __launch_bounds__(256) void ugemm(
    const __hip_bfloat16* __restrict__ W1T, const __hip_bfloat16* __restrict__ Cbf,
    const float* __restrict__ mp,
    float* __restrict__ Eh2p, float* __restrict__ Mup)
{
    __shared__ __align__(16) __hip_bfloat16 As[128 * 32];
    __shared__ __align__(16) __hip_bfloat16 Bs[128 * 32];
    const int tid = threadIdx.x, lane = tid & 63, wid = tid >> 6;
    const int n0 = blockIdx.x * 128, m0 = blockIdx.y * 128, p = blockIdx.z;
    const __hip_bfloat16* Ap = W1T + (size_t)p * HID * EMB;
    const int wr = wid >> 1, wc = wid & 1;
    const int l4 = lane >> 4, lc = lane & 15;

    f32x4 acc[4][4] = {};
    for (int k0 = 0; k0 < EMB; k0 += 32) {
        __syncthreads();
        #pragma unroll
        for (int r = 0; r < 2; ++r) {
            int t = r * 256 + tid;
            int row = t >> 2, ko = (t & 3) * 8;
            GL16(Ap + (size_t)(m0 + row) * EMB + k0 + ko, &As[(r * 256 + wid * 64) * 8]);
        }
        #pragma unroll
        for (int r = 0; r < 2; ++r) {
            int t = r * 256 + tid;
            int row = t >> 2, ko = (t & 3) * 8;
            GL16(Cbf + (size_t)(n0 + row) * EMB + k0 + ko, &Bs[(r * 256 + wid * 64) * 8]);
        }
        __syncthreads();
        const bf16x8* Av = (const bf16x8*)As;
        const bf16x8* Bv = (const bf16x8*)Bs;
        bf16x8 a[4], b[4];
        #pragma unroll
        for (int m = 0; m < 4; ++m) a[m] = Av[(wr * 64 + m * 16 + lc) * 4 + l4];
        #pragma unroll
        for (int n = 0; n < 4; ++n) b[n] = Bv[(wc * 64 + n * 16 + lc) * 4 + l4];
        #pragma unroll
        for (int m = 0; m < 4; ++m)
            #pragma unroll
            for (int n = 0; n < 4; ++n)
                acc[m][n] = __builtin_amdgcn_mfma_f32_16x16x32_bf16(a[m], b[n], acc[m][n], 0, 0, 0);
    }

    float mpv[4];
    #pragma unroll
    for (int n = 0; n < 4; ++n) mpv[n] = mp[n0 + wc * 64 + n * 16 + lc];
    #pragma unroll
    for (int m = 0; m < 4; ++m) {
        #pragma unroll
        for (int j = 0; j < 4; ++j) {
            int row = m0 + wr * 64 + m * 16 + l4 * 4 + j;
            const __hip_bfloat16* wrow = Ap + (size_t)row * EMB;
            float e2 = 0.f, mu = 0.f;
            #pragma unroll
            for (int n = 0; n < 4; ++n) {
                int col = n0 + wc * 64 + n * 16 + lc;
                float wv = bf2f(__builtin_bit_cast(unsigned short, wrow[col]));
                e2 += acc[m][n][j] * wv;
                mu += mpv[n] * wv;
            }
            e2 += __shfl_xor(e2, 1); e2 += __shfl_xor(e2, 2);
            e2 += __shfl_xor(e2, 4); e2 += __shfl_xor(e2, 8);
            mu += __shfl_xor(mu, 1); mu += __shfl_xor(mu, 2);
            mu += __shfl_xor(mu, 4); mu += __shfl_xor(mu, 8);
            if (lc == 0) {
                size_t idx = (((size_t)blockIdx.x * 2 + wc) * NPROJ + p) * HID + row;
                Eh2p[idx] = e2;
                Mup [idx] = mu;
            }
        }
    }
}

// ---------------------------------------------------------------------------
// Kernel 8: finalize (reduce 12 partials)
// ---------------------------------------------------------------------------
__global__ __launch_bounds__(256) void finalize(
    const float* __restrict__ Eh2p, const float* __restrict__ Mup,
    const float* __restrict__ gamma, const float* __restrict__ beta,
    float* __restrict__ sbuf, float* __restrict__ tbuf)
{
    int i = blockIdx.x * 256 + threadIdx.x;            // < 16384
    float e2 = 0.f, mu = 0.f;
    #pragma unroll
    for (int bx = 0; bx < 12; ++bx) {
        e2 += Eh2p[bx * (NPROJ * HID) + i];
        mu += Mup [bx * (NPROJ * HID) + i];
    }
    float var = e2 - mu * mu;
    float is  = rsqrtf(fmaxf(var, 0.0f) + 1e-5f);
    float sc  = gamma[i] * is;
    sbuf[i] = sc;
    tbuf[i] = beta[i] - mu * sc;
}

// ---------------------------------------------------------------------------
// Kernel 9: selected GEMM1 + fused BN+ReLU — 256x256 tile, 8 waves, BK=64,
// double-buffered 128KB LDS, XOR-swizzled (byte ^= (row&7)<<4 on both sides),
// stage-next-tile issued at tile start (loads fly across full tile compute),
// one vmcnt(0)+barrier per tile.  grid (16, 16), 512 threads.
// One m-block (256 rows) = one mask slot -> p = proj[blockIdx.y].
// ---------------------------------------------------------------------------
__global__ __launch_bounds__(512, 2) void gemm1_sel(
    const __hip_bfloat16* __restrict__ A, const __hip_bfloat16* __restrict__ W1T,
    const int* __restrict__ proj,
    const float* __restrict__ sbuf, const float* __restrict__ tbuf,
    __hip_bfloat16* __restrict__ hrelu)
{
    __shared__ __align__(16) short LS[2][32768];   // [buf][A 16384 | B 16384], 128 KB
    const int tid = threadIdx.x, lane = tid & 63, w = tid >> 6;
    const int wr = w >> 2, wc = w & 3;             // 2M x 4N waves
    const int lc = lane & 15, l4 = lane >> 4;
    const int n0 = blockIdx.x * 256, m0 = blockIdx.y * 256;
    const int p = proj[blockIdx.y];
    const __hip_bfloat16* Ag = A;
    const __hip_bfloat16* Bg = W1T + (size_t)p * HID * EMB;
    const bf16x8* LSv = (const bf16x8*)LS;

    // stage K-tile t into buffer sbf: each wave stages its own 4KB of A and B.
    // physical LDS byte P holds logical byte P ^ ((row&7)<<4)  (16B-chunk swap)
    const int st_row_l = lane >> 3;                // 0..7
    const int st_cs    = lane & 7;                 // physical 16B slot
    auto STAGE = [&](int sbf, int t) {
        #pragma unroll
        for (int ab = 0; ab < 2; ++ab) {
            const __hip_bfloat16* g = ab ? Bg : Ag;
            const int rbase = ab ? n0 : m0;
            #pragma unroll
            for (int i = 0; i < 4; ++i) {
                int row = w * 32 + i * 8 + st_row_l;
                int csl = st_cs ^ (row & 7);       // logical slot for this lane
                const __hip_bfloat16* src =
                    g + (size_t)(rbase + row) * EMB + t * 64 + csl * 8;
                char* dst = (char*)LS + ab * 32768 + sbf * 65536 + w * 4096 + i * 1024;
                GL16(src, dst);
            }
        }
    };

    f32x4 acc[8][4] = {};

    STAGE(0, 0);
    asm volatile("s_waitcnt vmcnt(0)" ::: "memory");
    __builtin_amdgcn_s_barrier();

    for (int t = 0; t < 12; ++t) {
        const int buf = t & 1;
        if (t + 1 < 12) STAGE(buf ^ 1, t + 1);     // flies across this tile's compute

        const int vbA = buf * 4096;                // bf16x8 units
        const int vbB = buf * 4096 + 2048;

        // B fragments for the whole tile (4 nf x 2 ks)
        bf16x8 bfr[4][2];
        #pragma unroll
        for (int nf = 0; nf < 4; ++nf) {
            int row_b = wc * 64 + nf * 16 + lc;
            #pragma unroll
            for (int ks = 0; ks < 2; ++ks)
                bfr[nf][ks] = LSv[vbB + row_b * 8 + ((ks * 4 + l4) ^ (row_b & 7))];
        }
        #pragma unroll
        for (int q = 0; q < 4; ++q) {
            bf16x8 afr[2][2];
            #pragma unroll
            for (int mf2 = 0; mf2 < 2; ++mf2) {
                int row_a = wr * 128 + (q * 2 + mf2) * 16 + lc;
                #pragma unroll
                for (int ks = 0; ks < 2; ++ks)
                    afr[mf2][ks] = LSv[vbA + row_a * 8 + ((ks * 4 + l4) ^ (row_a & 7))];
            }
            __builtin_amdgcn_s_setprio(1);
            #pragma unroll
            for (int mf2 = 0; mf2 < 2; ++mf2)
                #pragma unroll
                for (int nf = 0; nf < 4; ++nf)
                    #pragma unroll
                    for (int ks = 0; ks < 2; ++ks)
                        acc[q * 2 + mf2][nf] = __builtin_amdgcn_mfma_f32_16x16x32_bf16(
                            afr[mf2][ks], bfr[nf][ks], acc[q * 2 + mf2][nf], 0, 0, 0);
            __builtin_amdgcn_s_setprio(0);
        }

        asm volatile("s_waitcnt vmcnt(0)" ::: "memory");  // next tile staged (issued ~full tile ago)
        __builtin_amdgcn_s_barrier();                     // all waves done reading buf
    }

    // epilogue: BN + ReLU + store
    #pragma unroll
    for (int nf = 0; nf < 4; ++nf) {
        int col = n0 + wc * 64 + nf * 16 + lc;
        float s = sbuf[p * HID + col];
        float tt = tbuf[p * HID + col];
        #pragma unroll
        for (int mf = 0; mf < 8; ++mf)
            #pragma unroll
            for (int j = 0; j < 4; ++j) {
                int row = m0 + wr * 128 + mf * 16 + l4 * 4 + j;
                float v = fmaxf(acc[mf][nf][j] * s + tt, 0.0f);
                hrelu[(size_t)row * HID + col] = __float2bfloat16(v);
            }
    }
}

// ---------------------------------------------------------------------------
// Kernel 10: GEMM2 split-K, 128x128 tiles (cgemm structure):
// grid (16 nmask, 2 bc, 8): z = ct*4+kz, K-chunk = 1024. Partial stores.
// ---------------------------------------------------------------------------
__global__ __launch_bounds__(256) void gemm2(
    const __hip_bfloat16* __restrict__ Hn, const __hip_bfloat16* __restrict__ W2T,
    const int* __restrict__ proj, float* __restrict__ Opart)
{
    __shared__ __align__(16) __hip_bfloat16 As[128 * 32];
    __shared__ __align__(16) __hip_bfloat16 Bs[128 * 32];
    const int tid = threadIdx.x, lane = tid & 63, wid = tid >> 6;
    const int nmask = blockIdx.x;
    const int bc    = blockIdx.y;                 // 128-row chunk of 256 batch rows
    const int ct    = blockIdx.z >> 2, kz = blockIdx.z & 3;
    const int p = proj[nmask];
    const __hip_bfloat16* Ap = Hn + (size_t)(nmask * 256 + bc * 128) * HID;
    const __hip_bfloat16* Bp = W2T + ((size_t)p * OUT + ct * 128) * HID;
    float* Op = Opart + (size_t)kz * MROWS * OUT;
    const int wr = wid >> 1, wc = wid & 1;
    const int l4 = lane >> 4, lc = lane & 15;

    f32x4 acc[4][4] = {};
    for (int k0 = kz * 1024; k0 < kz * 1024 + 1024; k0 += 32) {
        __syncthreads();
        #pragma unroll
        for (int r = 0; r < 2; ++r) {
            int t = r * 256 + tid;
            int row = t >> 2, ko = (t & 3) * 8;
            GL16(Ap + (size_t)row * HID + k0 + ko, &As[(r * 256 + wid * 64) * 8]);
        }
        #pragma unroll
        for (int r = 0; r < 2; ++r) {
            int t = r * 256 + tid;
            int row = t >> 2, ko = (t & 3) * 8;
            GL16(Bp + (size_t)row * HID + k0 + ko, &Bs[(r * 256 + wid * 64) * 8]);
        }
        __syncthreads();
        const bf16x8* Av = (const bf16x8*)As;
        const bf16x8* Bv = (const bf16x8*)Bs;
        bf16x8 a[4], b[4];
        #pragma unroll
        for (int m = 0; m < 4; ++m) a[m] = Av[(wr * 64 + m * 16 + lc) * 4 + l4];
        #pragma unroll
        for (int n = 0; n < 4; ++n) b[n] = Bv[(wc * 64 + n * 16 + lc) * 4 + l4];
        #pragma unroll
        for (int m = 0; m < 4; ++m)
            #pragma unroll
            for (int n = 0; n < 4; ++n)
                acc[m][n] = __builtin_amdgcn_mfma_f32_16x16x32_bf16(a[m], b[n], acc[m][n], 0, 0, 0);
    }

    #pragma unroll
    for (int m = 0; m < 4; ++m)
        #pragma unroll
        for (int n = 0; n < 4; ++n)
            #pragma unroll
            for (int j = 0; j < 4; ++j) {
                int bb = bc * 128 + wr * 64 + m * 16 + l4 * 4 + j;
                int oc = ct * 128 + wc * 64 + n * 16 + lc;
                Op[((size_t)bb * NMASK + nmask) * OUT + oc] = acc[m][n][j];
            }
}

// ---------------------------------------------------------------------------
// Kernel 11: reduce 4 Opart slices + b2 -> out ; fused mask_ids tail
// ---------------------------------------------------------------------------
__global__ __launch_bounds__(256) void reduce_out(
    const float* __restrict__ Opart, const float* __restrict__ b2,
    const int* __restrict__ proj, const int* __restrict__ mids,
    float* __restrict__ out)
{
    int i = (blockIdx.x * 256 + threadIdx.x) * 4;   // < 4096*256
    float sx = 0.f, sy = 0.f, sz = 0.f, sw = 0.f;
    #pragma unroll
    for (int kz = 0; kz < 4; ++kz) {
        float4 v = *(const float4*)(Opart + (size_t)kz * MROWS * OUT + i);
        sx += v.x; sy += v.y; sz += v.z; sw += v.w;
    }
    int nm = (i >> 8) & 15;
    int p  = proj[nm];
    float4 bv = *(const float4*)(b2 + p * OUT + (i & 255));
    float4 r;
    r.x = sx + bv.x; r.y = sy + bv.y; r.z = sz + bv.z; r.w = sw + bv.w;
    *(float4*)(out + i) = r;
    if (blockIdx.x < 16) {
        int t = blockIdx.x * 256 + threadIdx.x;     // < 4096
        out[(size_t)MROWS * OUT + t] = (float)mids[t];
    }
}

// ---------------------------------------------------------------------------
extern "C" void kernel_launch(void* const* d_in, const int* in_sizes, int n_in,
                              void* d_out, int out_size, void* d_ws, size_t ws_size,
                              hipStream_t stream)
{
    const float* x     = (const float*)d_in[0];
    const float* masks = (const float*)d_in[1];
    const int*   proj  = (const int*)d_in[2];
    const int*   mids  = (const int*)d_in[3];
    const float* W1    = (const float*)d_in[4];
    // d_in[5] = b1: cancels exactly under training-mode BN -> unused
    const float* gamma = (const float*)d_in[6];
    const float* beta  = (const float*)d_in[7];
    const float* W2    = (const float*)d_in[8];
    const float* b2    = (const float*)d_in[9];
    float* out = (float*)d_out;

    char* ws = (char*)d_ws;
    __hip_bfloat16* pooledG = (__hip_bfloat16*)(ws);                   //  6,291,456
    __hip_bfloat16* W1T     = (__hip_bfloat16*)(ws + 6291456);         // 25,165,824
    __hip_bfloat16* W2T     = (__hip_bfloat16*)(ws + 31457280);        //  8,388,608
    float*          mp      = (float*)(ws + 39845888);                 //      3,072
    float*          Eh2p    = (float*)(ws + 39848960);                 //    786,432
    float*          Mup     = (float*)(ws + 40635392);                 //    786,432
    float*          sbuf    = (float*)(ws + 41421824);                 //     65,536
    float*          tbuf    = (float*)(ws + 41487360);                 //     65,536
    char* R = ws + 41552896;
    __hip_bfloat16* pooledT = (__hip_bfloat16*)(R);                    //  6,291,456
    float*          Cpart   = (float*)(R + 6291456);                   // 18,874,368
    __hip_bfloat16* Cbf     = (__hip_bfloat16*)(R + 25165824);         //  1,179,648
    __hip_bfloat16* hrelu   = (__hip_bfloat16*)(R);                    // 33,554,432
    float*          Opart   = (float*)(R + 33554432);                  // 16,777,216

    pool_mfma<<<dim3(4, BS), 256, 0, stream>>>(x, masks, pooledG);
    transpose_cvt<<<dim3(HID / 64, EMB / 64, NPROJ), 256, 0, stream>>>(W1, W1T, EMB, HID);
    transpose_cvt<<<dim3(OUT / 64, HID / 64, NPROJ), 256, 0, stream>>>(W2, W2T, HID, OUT);
    transpose_pg<<<dim3(EMB / 64, MROWS / 64), 256, 0, stream>>>(pooledG, pooledT);
    meanpool<<<EMB, 256, 0, stream>>>(pooledT, mp);
    cgemm<<<dim3(6, 6, 8), 256, 0, stream>>>(pooledT, Cpart);
    cvt_c<<<(EMB * EMB) / 1024, 256, 0, stream>>>(Cpart, Cbf);
    ugemm<<<dim3(6, 32, 4), 256, 0, stream>>>(W1T, Cbf, mp, Eh2p, Mup);
    finalize<<<(NPROJ * HID) / 256, 256, 0, stream>>>(Eh2p, Mup, gamma, beta, sbuf, tbuf);
    gemm1_sel<<<dim3(HID / 256, MROWS / 256), 512, 0, stream>>>(pooledG, W1T, proj, sbuf, tbuf, hrelu);
    gemm2<<<dim3(NMASK, 2, 8), 256, 0, stream>>>(hrelu, W2T, proj, Opart);
    reduce_out<<<(MROWS * OUT) / 1024, 256, 0, stream>>>(Opart, b2, proj, mids, out);
}

// Round 10
// 202.519 us; speedup vs baseline: 1.6861x; 1.0114x over previous
//
#include <hip/hip_runtime.h>
#include <hip/hip_bf16.h>

// Problem constants
#define BS 256
#define EMB 768
#define HW 196          // 14*14
#define NMASK 16
#define HID 4096
#define OUT 256
#define NPROJ 4
#define MROWS 4096      // BS*NMASK

typedef __attribute__((ext_vector_type(8))) short bf16x8;
typedef __attribute__((ext_vector_type(4))) float f32x4;
typedef __attribute__((ext_vector_type(8))) unsigned short u16x8;

__device__ inline float bf2f(unsigned short u) {
    unsigned int x = ((unsigned int)u) << 16;
    return __builtin_bit_cast(float, x);
}
__device__ inline short f2bfs(float f) {
    return __builtin_bit_cast(short, __float2bfloat16(f));
}

// async global->LDS, 16B per lane; lds base must be wave-uniform
#define GL16(gptr, lptr)                                                     \
    __builtin_amdgcn_global_load_lds(                                        \
        (const __attribute__((address_space(1))) void*)(gptr),               \
        (__attribute__((address_space(3))) void*)(lptr), 16, 0, 0)

// ---------------------------------------------------------------------------
// Kernel 1: masked mean pooling via MFMA.
// grid (4, 256): blockIdx.x = e-chunk of 192, blockIdx.y = b. 4 waves x 48 e.
// ---------------------------------------------------------------------------
__global__ __launch_bounds__(256) void pool_mfma(
    const float* __restrict__ x, const float* __restrict__ masks,
    __hip_bfloat16* __restrict__ pooledG)
{
    __shared__ __align__(16) short afr[7 * 64 * 8];   // A-fragments, 7 KB
    __shared__ float inv[NMASK];
    const int ec = blockIdx.x, b = blockIdx.y, tid = threadIdx.x;
    const float* mb = masks + (size_t)b * NMASK * HW;

    for (int s = tid; s < 7 * 64; s += 256) {
        int m = s & 15, kb = ((s >> 4) & 3) * 8 + (s >> 6) * 32;
        short v[8];
        #pragma unroll
        for (int j = 0; j < 8; ++j) {
            int kk = kb + j;
            v[j] = (kk < HW) ? f2bfs(mb[m * HW + kk]) : (short)0;
        }
        #pragma unroll
        for (int j = 0; j < 8; ++j) afr[s * 8 + j] = v[j];
    }
    if (tid >= 192) {
        int l = tid - 192, m = l >> 2, q = l & 3;
        float a = 0.f;
        for (int hw = q; hw < HW; hw += 4) a += mb[m * HW + hw];
        a += __shfl_xor(a, 1);
        a += __shfl_xor(a, 2);
        if (q == 0) inv[m] = 1.0f / fmaxf(a, 1.0f);
    }
    __syncthreads();

    const int lane = tid & 63, w = tid >> 6;
    const int lc = lane & 15, l4 = lane >> 4;
    const int ebase = ec * 192 + w * 48;
    const bf16x8* afv = (const bf16x8*)afr;
    f32x4 acc[3] = {};

    const float* xb0 = x + ((size_t)b * EMB + ebase + lc) * HW;

    for (int kc = 0; kc < 6; ++kc) {
        bf16x8 af = afv[kc * 64 + lane];
        float4 u[3][2];
        #pragma unroll
        for (int t = 0; t < 3; ++t) {
            const float* xr = xb0 + (size_t)(t * 16) * HW + kc * 32 + l4 * 8;
            u[t][0] = *(const float4*)(xr);
            u[t][1] = *(const float4*)(xr + 4);
        }
        #pragma unroll
        for (int t = 0; t < 3; ++t) {
            bf16x8 bf;
            bf[0] = f2bfs(u[t][0].x); bf[1] = f2bfs(u[t][0].y);
            bf[2] = f2bfs(u[t][0].z); bf[3] = f2bfs(u[t][0].w);
            bf[4] = f2bfs(u[t][1].x); bf[5] = f2bfs(u[t][1].y);
            bf[6] = f2bfs(u[t][1].z); bf[7] = f2bfs(u[t][1].w);
            acc[t] = __builtin_amdgcn_mfma_f32_16x16x32_bf16(af, bf, acc[t], 0, 0, 0);
        }
    }
    {   // tail K-chunk
        bf16x8 af = afv[6 * 64 + lane];
        #pragma unroll
        for (int t = 0; t < 3; ++t) {
            bf16x8 bf = {};
            if (l4 == 0) {
                float4 u0 = *(const float4*)(xb0 + (size_t)(t * 16) * HW + 192);
                bf[0] = f2bfs(u0.x); bf[1] = f2bfs(u0.y);
                bf[2] = f2bfs(u0.z); bf[3] = f2bfs(u0.w);
            }
            acc[t] = __builtin_amdgcn_mfma_f32_16x16x32_bf16(af, bf, acc[t], 0, 0, 0);
        }
    }

    #pragma unroll
    for (int t = 0; t < 3; ++t) {
        int e = ebase + t * 16 + lc;
        #pragma unroll
        for (int j = 0; j < 4; ++j) {
            int m = l4 * 4 + j;
            pooledG[((size_t)m * 256 + b) * EMB + e] =
                __float2bfloat16(acc[t][j] * inv[m]);
        }
    }
}

// ---------------------------------------------------------------------------
// Kernel 2: fused prep — W1 transpose+cvt (3072 blocks), W2 transpose+cvt
// (1024 blocks), pooledG bf16 transpose (768 blocks).  grid 4864.
// ---------------------------------------------------------------------------
__global__ __launch_bounds__(256) void prep(
    const float* __restrict__ W1, const float* __restrict__ W2,
    const __hip_bfloat16* __restrict__ pg,
    __hip_bfloat16* __restrict__ W1T, __hip_bfloat16* __restrict__ W2T,
    __hip_bfloat16* __restrict__ pgT)
{
    __shared__ __align__(16) char sm[64 * 65 * 4];
    const int bid = blockIdx.x, tid = threadIdx.x;
    if (bid < 4096) {
        const float* src; __hip_bfloat16* dst; int R, C, x, y, z;
        if (bid < 3072) { z = bid / 768; int r = bid % 768; x = r % 64; y = r / 64;
                          src = W1; dst = W1T; R = EMB; C = HID; }
        else            { int b2 = bid - 3072; z = b2 / 256; int r = b2 % 256;
                          x = r % 4; y = r / 4; src = W2; dst = W2T; R = HID; C = OUT; }
        float (*tile)[65] = (float(*)[65])sm;
        const float* s = src + (size_t)z * R * C;
        __hip_bfloat16* d = dst + (size_t)z * R * C;
        const int c0 = x * 64, r0 = y * 64;
        for (int i = tid; i < 4096; i += 256) {
            int r = i >> 6, c = i & 63;
            tile[r][c] = s[(size_t)(r0 + r) * C + c0 + c];
        }
        __syncthreads();
        for (int i = tid; i < 4096; i += 256) {
            int c = i >> 6, r = i & 63;
            d[(size_t)(c0 + c) * R + r0 + r] = __float2bfloat16(tile[r][c]);
        }
    } else {
        const int b3 = bid - 4096;            // (12 x, 64 y)
        const int x = b3 % 12, y = b3 / 12;
        __hip_bfloat16 (*tile)[65] = (__hip_bfloat16(*)[65])sm;
        const int c0 = x * 64, r0 = y * 64;
        for (int i = tid; i < 4096; i += 256) {
            int r = i >> 6, c = i & 63;
            tile[r][c] = pg[(size_t)(r0 + r) * EMB + c0 + c];
        }
        __syncthreads();
        for (int i = tid; i < 4096; i += 256) {
            int c = i >> 6, r = i & 63;
            pgT[(size_t)(c0 + c) * MROWS + r0 + r] = tile[r][c];
        }
    }
}

// ---------------------------------------------------------------------------
// Kernel 3: mp[e] = (1/4096) sum_r pooledT[e][r]
// ---------------------------------------------------------------------------
__global__ __launch_bounds__(256) void meanpool(
    const __hip_bfloat16* __restrict__ PT, float* __restrict__ mp)
{
    const int e = blockIdx.x, tid = threadIdx.x;
    const u16x8* p = (const u16x8*)(PT + (size_t)e * MROWS);
    u16x8 v1 = p[tid], v2 = p[tid + 256];
    float s = 0.f;
    #pragma unroll
    for (int j = 0; j < 8; ++j) s += bf2f((unsigned short)v1[j]) + bf2f((unsigned short)v2[j]);
    #pragma unroll
    for (int o = 1; o < 64; o <<= 1) s += __shfl_xor(s, o);
    __shared__ float wsum[4];
    if ((tid & 63) == 0) wsum[tid >> 6] = s;
    __syncthreads();
    if (tid == 0) mp[e] = (wsum[0] + wsum[1] + wsum[2] + wsum[3]) * (1.0f / 4096.0f);
}

// ---------------------------------------------------------------------------
// Kernel 4: C GEMM (split-K, partial stores): Cpart[kz][i][j]
// grid (6, 6, 8)  K-chunk = 512.
// ---------------------------------------------------------------------------
__global__ __launch_bounds__(256) void cgemm(
    const __hip_bfloat16* __restrict__ PT, float* __restrict__ Cpart)
{
    __shared__ __align__(16) __hip_bfloat16 As[128 * 32];
    __shared__ __align__(16) __hip_bfloat16 Bs[128 * 32];
    const int tid = threadIdx.x, lane = tid & 63, wid = tid >> 6;
    const int n0 = blockIdx.x * 128, m0 = blockIdx.y * 128, kbase = blockIdx.z * 512;
    float* Cp = Cpart + (size_t)blockIdx.z * EMB * EMB;
    const int wr = wid >> 1, wc = wid & 1;
    const int l4 = lane >> 4, lc = lane & 15;

    f32x4 acc[4][4] = {};
    for (int k0 = kbase; k0 < kbase + 512; k0 += 32) {
        __syncthreads();
        #pragma unroll
        for (int r = 0; r < 2; ++r) {
            int t = r * 256 + tid;
            int row = t >> 2, ko = (t & 3) * 8;
            GL16(PT + (size_t)(m0 + row) * MROWS + k0 + ko, &As[(r * 256 + wid * 64) * 8]);
        }
        #pragma unroll
        for (int r = 0; r < 2; ++r) {
            int t = r * 256 + tid;
            int row = t >> 2, ko = (t & 3) * 8;
            GL16(PT + (size_t)(n0 + row) * MROWS + k0 + ko, &Bs[(r * 256 + wid * 64) * 8]);
        }
        __syncthreads();
        const bf16x8* Av = (const bf16x8*)As;
        const bf16x8* Bv = (const bf16x8*)Bs;
        bf16x8 a[4], b[4];
        #pragma unroll
        for (int m = 0; m < 4; ++m) a[m] = Av[(wr * 64 + m * 16 + lc) * 4 + l4];
        #pragma unroll
        for (int n = 0; n < 4; ++n) b[n] = Bv[(wc * 64 + n * 16 + lc) * 4 + l4];
        #pragma unroll
        for (int m = 0; m < 4; ++m)
            #pragma unroll
            for (int n = 0; n < 4; ++n)
                acc[m][n] = __builtin_amdgcn_mfma_f32_16x16x32_bf16(a[m], b[n], acc[m][n], 0, 0, 0);
    }
    #pragma unroll
    for (int m = 0; m < 4; ++m)
        #pragma unroll
        for (int n = 0; n < 4; ++n)
            #pragma unroll
            for (int j = 0; j < 4; ++j) {
                int row = m0 + wr * 64 + m * 16 + l4 * 4 + j;
                int col = n0 + wc * 64 + n * 16 + lc;
                Cp[(size_t)row * EMB + col] = acc[m][n][j];
            }
}

// ---------------------------------------------------------------------------
// Kernel 5: reduce 8 Cpart slices -> Cbf bf16 with 1/N fold
// ---------------------------------------------------------------------------
__global__ __launch_bounds__(256) void cvt_c(
    const float* __restrict__ Cpart, __hip_bfloat16* __restrict__ Cbf)
{
    int i = (blockIdx.x * 256 + threadIdx.x) * 4;   // < 768*768
    float sx = 0.f, sy = 0.f, sz = 0.f, sw = 0.f;
    #pragma unroll
    for (int kz = 0; kz < 8; ++kz) {
        float4 v = *(const float4*)(Cpart + (size_t)kz * EMB * EMB + i);
        sx += v.x; sy += v.y; sz += v.z; sw += v.w;
    }
    const float s = 1.0f / 4096.0f;
    Cbf[i + 0] = __float2bfloat16(sx * s);
    Cbf[i + 1] = __float2bfloat16(sy * s);
    Cbf[i + 2] = __float2bfloat16(sz * s);
    Cbf[i + 3] = __float2bfloat16(sw * s);
}

// ---------------------------------------------------------------------------
// Kernel 6: U GEMM + fused stats (partial stores indexed by (bx*2+wc)).
// grid (6, 32, 4) -> 12 partial slices.
// ---------------------------------------------------------------------------
__global__ __launch_bounds__(256) void ugemm(
    const __hip_bfloat16* __restrict__ W1T, const __hip_bfloat16* __restrict__ Cbf,
    const float* __restrict__ mp,
    float* __restrict__ Eh2p, float* __restrict__ Mup)
{
    __shared__ __align__(16) __hip_bfloat16 As[128 * 32];
    __shared__ __align__(16) __hip_bfloat16 Bs[128 * 32];
    const int tid = threadIdx.x, lane = tid & 63, wid = tid >> 6;
    const int n0 = blockIdx.x * 128, m0 = blockIdx.y * 128, p = blockIdx.z;
    const __hip_bfloat16* Ap = W1T + (size_t)p * HID * EMB;
    const int wr = wid >> 1, wc = wid & 1;
    const int l4 = lane >> 4, lc = lane & 15;

    f32x4 acc[4][4] = {};
    for (int k0 = 0; k0 < EMB; k0 += 32) {
        __syncthreads();
        #pragma unroll
        for (int r = 0; r < 2; ++r) {
            int t = r * 256 + tid;
            int row = t >> 2, ko = (t & 3) * 8;
            GL16(Ap + (size_t)(m0 + row) * EMB + k0 + ko, &As[(r * 256 + wid * 64) * 8]);
        }
        #pragma unroll
        for (int r = 0; r < 2; ++r) {
            int t = r * 256 + tid;
            int row = t >> 2, ko = (t & 3) * 8;
            GL16(Cbf + (size_t)(n0 + row) * EMB + k0 + ko, &Bs[(r * 256 + wid * 64) * 8]);
        }
        __syncthreads();
        const bf16x8* Av = (const bf16x8*)As;
        const bf16x8* Bv = (const bf16x8*)Bs;
        bf16x8 a[4], b[4];
        #pragma unroll
        for (int m = 0; m < 4; ++m) a[m] = Av[(wr * 64 + m * 16 + lc) * 4 + l4];
        #pragma unroll
        for (int n = 0; n < 4; ++n) b[n] = Bv[(wc * 64 + n * 16 + lc) * 4 + l4];
        #pragma unroll
        for (int m = 0; m < 4; ++m)
            #pragma unroll
            for (int n = 0; n < 4; ++n)
                acc[m][n] = __builtin_amdgcn_mfma_f32_16x16x32_bf16(a[m], b[n], acc[m][n], 0, 0, 0);
    }

    float mpv[4];
    #pragma unroll
    for (int n = 0; n < 4; ++n) mpv[n] = mp[n0 + wc * 64 + n * 16 + lc];
    #pragma unroll
    for (int m = 0; m < 4; ++m) {
        #pragma unroll
        for (int j = 0; j < 4; ++j) {
            int row = m0 + wr * 64 + m * 16 + l4 * 4 + j;
            const __hip_bfloat16* wrow = Ap + (size_t)row * EMB;
            float e2 = 0.f, mu = 0.f;
            #pragma unroll
            for (int n = 0; n < 4; ++n) {
                int col = n0 + wc * 64 + n * 16 + lc;
                float wv = bf2f(__builtin_bit_cast(unsigned short, wrow[col]));
                e2 += acc[m][n][j] * wv;
                mu += mpv[n] * wv;
            }
            e2 += __shfl_xor(e2, 1); e2 += __shfl_xor(e2, 2);
            e2 += __shfl_xor(e2, 4); e2 += __shfl_xor(e2, 8);
            mu += __shfl_xor(mu, 1); mu += __shfl_xor(mu, 2);
            mu += __shfl_xor(mu, 4); mu += __shfl_xor(mu, 8);
            if (lc == 0) {
                size_t idx = (((size_t)blockIdx.x * 2 + wc) * NPROJ + p) * HID + row;
                Eh2p[idx] = e2;
                Mup [idx] = mu;
            }
        }
    }
}

// ---------------------------------------------------------------------------
// Kernel 7: finalize (reduce 12 partials)
// ---------------------------------------------------------------------------
__global__ __launch_bounds__(256) void finalize(
    const float* __restrict__ Eh2p, const float* __restrict__ Mup,
    const float* __restrict__ gamma, const float* __restrict__ beta,
    float* __restrict__ sbuf, float* __restrict__ tbuf)
{
    int i = blockIdx.x * 256 + threadIdx.x;            // < 16384
    float e2 = 0.f, mu = 0.f;
    #pragma unroll
    for (int bx = 0; bx < 12; ++bx) {
        e2 += Eh2p[bx * (NPROJ * HID) + i];
        mu += Mup [bx * (NPROJ * HID) + i];
    }
    float var = e2 - mu * mu;
    float is  = rsqrtf(fmaxf(var, 0.0f) + 1e-5f);
    float sc  = gamma[i] * is;
    sbuf[i] = sc;
    tbuf[i] = beta[i] - mu * sc;
}

// ---------------------------------------------------------------------------
// Kernel 8: selected GEMM1 + fused BN+ReLU — 256x256 tile, 8 waves, BK=32,
// 3-slot LDS ring (96 KB = 3 x 2048 bf16x8 chunks/slot: A first 1024, B next
// 1024), counted vmcnt(4) (never 0 in steady state).  XOR swizzle phys_slot =
// l4 ^ (row&3) on both sides.  grid (16, 16), 512 threads.  p = proj[by].
// R9 bug fixed: read base was (t%3)*4096 (+2048 for B) — wrong slot; now
// (t%3)*2048 (+1024 for B), matching STAGE's byte base (t%3)*32768.
// ---------------------------------------------------------------------------
__global__ __launch_bounds__(512, 2) void gemm1_sel(
    const __hip_bfloat16* __restrict__ A, const __hip_bfloat16* __restrict__ W1T,
    const int* __restrict__ proj,
    const float* __restrict__ sbuf, const float* __restrict__ tbuf,
    __hip_bfloat16* __restrict__ hrelu)
{
    __shared__ __align__(16) short LS[3 * 16384];  // slot: A 8192 shorts | B 8192 shorts
    const int tid = threadIdx.x, lane = tid & 63, w = tid >> 6;
    const int wr = w >> 2, wc = w & 3;             // 2M x 4N waves
    const int lc = lane & 15, l4 = lane >> 4;
    const int n0 = blockIdx.x * 256, m0 = blockIdx.y * 256;
    const int p = proj[blockIdx.y];
    const __hip_bfloat16* Ag = A;
    const __hip_bfloat16* Bg = W1T + (size_t)p * HID * EMB;
    const bf16x8* LSv = (const bf16x8*)LS;

    // stage K-chunk t (cols t*32..+31) into slot t%3.  Per operand: 1024
    // 16B-chunks; thread's chunk c = (w*2+i)*64 + lane -> row c>>2, phys c&3.
    // phys slot ps holds logical slot ps ^ (row&3)  (pre-swizzled source).
    auto STAGE = [&](int t) {
        const int sb = (t % 3) * 32768;            // byte base of slot
        #pragma unroll
        for (int ab = 0; ab < 2; ++ab) {
            const __hip_bfloat16* g = ab ? Bg : Ag;
            const int rbase = ab ? n0 : m0;
            #pragma unroll
            for (int i = 0; i < 2; ++i) {
                int c = (w * 2 + i) * 64 + lane;
                int row = c >> 2, ps = c & 3;
                int ls = ps ^ (row & 3);
                const __hip_bfloat16* src =
                    g + (size_t)(rbase + row) * EMB + t * 32 + ls * 8;
                GL16(src, (char*)LS + sb + ab * 16384 + (w * 2 + i) * 1024);
            }
        }
    };

    f32x4 acc[8][4] = {};

    STAGE(0);
    STAGE(1);
    asm volatile("s_waitcnt vmcnt(4)" ::: "memory");   // tile 0 resident
    __builtin_amdgcn_s_barrier();

    for (int t = 0; t < 24; ++t) {
        if (t + 2 < 24) STAGE(t + 2);                  // into slot (t+2)%3 (safe)
        const int vb = (t % 3) * 2048;                 // bf16x8 base of slot (FIXED)

        bf16x8 bfr[4];
        #pragma unroll
        for (int nf = 0; nf < 4; ++nf) {
            int rb = wc * 64 + nf * 16 + lc;
            bfr[nf] = LSv[vb + 1024 + rb * 4 + (l4 ^ (rb & 3))];
        }
        #pragma unroll
        for (int q = 0; q < 4; ++q) {
            bf16x8 afr[2];
            #pragma unroll
            for (int m2 = 0; m2 < 2; ++m2) {
                int ra = wr * 128 + (q * 2 + m2) * 16 + lc;
                afr[m2] = LSv[vb + ra * 4 + (l4 ^ (ra & 3))];
            }
            __builtin_amdgcn_s_setprio(1);
            #pragma unroll
            for (int m2 = 0; m2 < 2; ++m2)
                #pragma unroll
                for (int nf = 0; nf < 4; ++nf)
                    acc[q * 2 + m2][nf] = __builtin_amdgcn_mfma_f32_16x16x32_bf16(
                        afr[m2], bfr[nf], acc[q * 2 + m2][nf], 0, 0, 0);
            __builtin_amdgcn_s_setprio(0);
        }

        if (t + 2 < 24) {
            asm volatile("s_waitcnt vmcnt(4)" ::: "memory");  // t+1 resident; t+2 in flight
            __builtin_amdgcn_s_barrier();
        } else if (t + 2 == 24) {                      // t == 22: last staged tile = 23
            asm volatile("s_waitcnt vmcnt(0)" ::: "memory");
            __builtin_amdgcn_s_barrier();
        }
    }

    // epilogue: BN + ReLU + store
    #pragma unroll
    for (int nf = 0; nf < 4; ++nf) {
        int col = n0 + wc * 64 + nf * 16 + lc;
        float s = sbuf[p * HID + col];
        float tt = tbuf[p * HID + col];
        #pragma unroll
        for (int mf = 0; mf < 8; ++mf)
            #pragma unroll
            for (int j = 0; j < 4; ++j) {
                int row = m0 + wr * 128 + mf * 16 + l4 * 4 + j;
                float v = fmaxf(acc[mf][nf][j] * s + tt, 0.0f);
                hrelu[(size_t)row * HID + col] = __float2bfloat16(v);
            }
    }
}

// ---------------------------------------------------------------------------
// Kernel 9: GEMM2 split-K, 128x128 tiles:
// grid (16 nmask, 2 bc, 8): z = ct*4+kz, K-chunk = 1024. Partial stores.
// ---------------------------------------------------------------------------
__global__ __launch_bounds__(256) void gemm2(
    const __hip_bfloat16* __restrict__ Hn, const __hip_bfloat16* __restrict__ W2T,
    const int* __restrict__ proj, float* __restrict__ Opart)
{
    __shared__ __align__(16) __hip_bfloat16 As[128 * 32];
    __shared__ __align__(16) __hip_bfloat16 Bs[128 * 32];
    const int tid = threadIdx.x, lane = tid & 63, wid = tid >> 6;
    const int nmask = blockIdx.x;
    const int bc    = blockIdx.y;
    const int ct    = blockIdx.z >> 2, kz = blockIdx.z & 3;
    const int p = proj[nmask];
    const __hip_bfloat16* Ap = Hn + (size_t)(nmask * 256 + bc * 128) * HID;
    const __hip_bfloat16* Bp = W2T + ((size_t)p * OUT + ct * 128) * HID;
    float* Op = Opart + (size_t)kz * MROWS * OUT;
    const int wr = wid >> 1, wc = wid & 1;
    const int l4 = lane >> 4, lc = lane & 15;

    f32x4 acc[4][4] = {};
    for (int k0 = kz * 1024; k0 < kz * 1024 + 1024; k0 += 32) {
        __syncthreads();
        #pragma unroll
        for (int r = 0; r < 2; ++r) {
            int t = r * 256 + tid;
            int row = t >> 2, ko = (t & 3) * 8;
            GL16(Ap + (size_t)row * HID + k0 + ko, &As[(r * 256 + wid * 64) * 8]);
        }
        #pragma unroll
        for (int r = 0; r < 2; ++r) {
            int t = r * 256 + tid;
            int row = t >> 2, ko = (t & 3) * 8;
            GL16(Bp + (size_t)row * HID + k0 + ko, &Bs[(r * 256 + wid * 64) * 8]);
        }
        __syncthreads();
        const bf16x8* Av = (const bf16x8*)As;
        const bf16x8* Bv = (const bf16x8*)Bs;
        bf16x8 a[4], b[4];
        #pragma unroll
        for (int m = 0; m < 4; ++m) a[m] = Av[(wr * 64 + m * 16 + lc) * 4 + l4];
        #pragma unroll
        for (int n = 0; n < 4; ++n) b[n] = Bv[(wc * 64 + n * 16 + lc) * 4 + l4];
        #pragma unroll
        for (int m = 0; m < 4; ++m)
            #pragma unroll
            for (int n = 0; n < 4; ++n)
                acc[m][n] = __builtin_amdgcn_mfma_f32_16x16x32_bf16(a[m], b[n], acc[m][n], 0, 0, 0);
    }

    #pragma unroll
    for (int m = 0; m < 4; ++m)
        #pragma unroll
        for (int n = 0; n < 4; ++n)
            #pragma unroll
            for (int j = 0; j < 4; ++j) {
                int bb = bc * 128 + wr * 64 + m * 16 + l4 * 4 + j;
                int oc = ct * 128 + wc * 64 + n * 16 + lc;
                Op[((size_t)bb * NMASK + nmask) * OUT + oc] = acc[m][n][j];
            }
}

// ---------------------------------------------------------------------------
// Kernel 10: reduce 4 Opart slices + b2 -> out ; fused mask_ids tail
// ---------------------------------------------------------------------------
__global__ __launch_bounds__(256) void reduce_out(
    const float* __restrict__ Opart, const float* __restrict__ b2,
    const int* __restrict__ proj, const int* __restrict__ mids,
    float* __restrict__ out)
{
    int i = (blockIdx.x * 256 + threadIdx.x) * 4;   // < 4096*256
    float sx = 0.f, sy = 0.f, sz = 0.f, sw = 0.f;
    #pragma unroll
    for (int kz = 0; kz < 4; ++kz) {
        float4 v = *(const float4*)(Opart + (size_t)kz * MROWS * OUT + i);
        sx += v.x; sy += v.y; sz += v.z; sw += v.w;
    }
    int nm = (i >> 8) & 15;
    int p  = proj[nm];
    float4 bv = *(const float4*)(b2 + p * OUT + (i & 255));
    float4 r;
    r.x = sx + bv.x; r.y = sy + bv.y; r.z = sz + bv.z; r.w = sw + bv.w;
    *(float4*)(out + i) = r;
    if (blockIdx.x < 16) {
        int t = blockIdx.x * 256 + threadIdx.x;     // < 4096
        out[(size_t)MROWS * OUT + t] = (float)mids[t];
    }
}

// ---------------------------------------------------------------------------
extern "C" void kernel_launch(void* const* d_in, const int* in_sizes, int n_in,
                              void* d_out, int out_size, void* d_ws, size_t ws_size,
                              hipStream_t stream)
{
    const float* x     = (const float*)d_in[0];
    const float* masks = (const float*)d_in[1];
    const int*   proj  = (const int*)d_in[2];
    const int*   mids  = (const int*)d_in[3];
    const float* W1    = (const float*)d_in[4];
    // d_in[5] = b1: cancels exactly under training-mode BN -> unused
    const float* gamma = (const float*)d_in[6];
    const float* beta  = (const float*)d_in[7];
    const float* W2    = (const float*)d_in[8];
    const float* b2    = (const float*)d_in[9];
    float* out = (float*)d_out;

    char* ws = (char*)d_ws;
    __hip_bfloat16* pooledG = (__hip_bfloat16*)(ws);                   //  6,291,456
    __hip_bfloat16* W1T     = (__hip_bfloat16*)(ws + 6291456);         // 25,165,824
    __hip_bfloat16* W2T     = (__hip_bfloat16*)(ws + 31457280);        //  8,388,608
    float*          mp      = (float*)(ws + 39845888);                 //      3,072
    float*          Eh2p    = (float*)(ws + 39848960);                 //    786,432
    float*          Mup     = (float*)(ws + 40635392);                 //    786,432
    float*          sbuf    = (float*)(ws + 41421824);                 //     65,536
    float*          tbuf    = (float*)(ws + 41487360);                 //     65,536
    char* R = ws + 41552896;
    __hip_bfloat16* pooledT = (__hip_bfloat16*)(R);                    //  6,291,456
    float*          Cpart   = (float*)(R + 6291456);                   // 18,874,368
    __hip_bfloat16* Cbf     = (__hip_bfloat16*)(R + 25165824);         //  1,179,648
    __hip_bfloat16* hrelu   = (__hip_bfloat16*)(R);                    // 33,554,432
    float*          Opart   = (float*)(R + 33554432);                  // 16,777,216

    pool_mfma<<<dim3(4, BS), 256, 0, stream>>>(x, masks, pooledG);
    prep<<<4864, 256, 0, stream>>>(W1, W2, pooledG, W1T, W2T, pooledT);
    meanpool<<<EMB, 256, 0, stream>>>(pooledT, mp);
    cgemm<<<dim3(6, 6, 8), 256, 0, stream>>>(pooledT, Cpart);
    cvt_c<<<(EMB * EMB) / 1024, 256, 0, stream>>>(Cpart, Cbf);
    ugemm<<<dim3(6, 32, 4), 256, 0, stream>>>(W1T, Cbf, mp, Eh2p, Mup);
    finalize<<<(NPROJ * HID) / 256, 256, 0, stream>>>(Eh2p, Mup, gamma, beta, sbuf, tbuf);
    gemm1_sel<<<dim3(HID / 256, MROWS / 256), 512, 0, stream>>>(pooledG, W1T, proj, sbuf, tbuf, hrelu);
    gemm2<<<dim3(NMASK, 2, 8), 256, 0, stream>>>(hrelu, W2T, proj, Opart);
    reduce_out<<<(MROWS * OUT) / 1024, 256, 0, stream>>>(Opart, b2, proj, mids, out);
}